// Round 1
// 5078.120 us; speedup vs baseline: 1.0549x; 1.0549x over previous
//
#include <hip/hip_runtime.h>
#include <math.h>

typedef _Float16 f16;
typedef __attribute__((ext_vector_type(8))) _Float16 half8;
typedef __attribute__((ext_vector_type(4))) float f32x4;

static __device__ __forceinline__ float sigmoid_f(float x) { return 1.0f / (1.0f + expf(-x)); }

// exact split: x == (float)hi + (float)lo / 4096 (lo pre-scaled to dodge denormals)
static __device__ __forceinline__ void splitf(float x, f16& hi, f16& lo) {
    hi = (f16)x;
    float r = x - (float)hi;
    lo = (f16)(r * 4096.0f);
}

// ---------------------------------------------------------------------------
// Tap-decomposed implicit-GEMM conv, f16 MFMA, 2-term activation split,
// fp32 accumulate.  COALESCED layouts (see previous session notes).
// Now a __device__ body so independent pipeline stages can be horizontally
// fused into one launch (occupancy was the bottleneck: 18% from 2 waves/SIMD).
// ---------------------------------------------------------------------------
template <int KH, int KW, int KPT, int MODE, int NG, int NOC, int D,
          int CBI, int KB0, int WPI, int PIXPI,
          int WSH, int HWOUT, int OC, int STRIDE, int POFF,
          int CBO, int OCH0, int WPO, int PIXPO>
static __device__ __forceinline__ void gemm_conv_body(
    int bx, int by, int b,
    const f16* Ah, const f16* Al, const f16* __restrict__ Wt,
    const float* __restrict__ bias, const float* __restrict__ zbuf,
    float* zout, f16* Oh, f16* Ol)
{
    constexpr int NSTEP = KH * KW * KPT;
    constexpr int WOUT  = 1 << WSH;
    constexpr int OCB   = OC / 16;
    static_assert(NSTEP % D == 0, "NSTEP divisible by D");

    const int lane = threadIdx.x & 63;
    const int wave = threadIdx.x >> 6;
    const int pixbase = (bx * 4 + wave) * (NG * 16);
    const int ocbase  = by * (NOC * 16);

    const f16* ph[NG];
    const f16* pl[NG];
#pragma unroll
    for (int g = 0; g < NG; ++g) {
        int apix = pixbase + 16 * g + (lane & 15);
        int y = apix >> WSH, x = apix & (WOUT - 1);
        int p0 = (y * STRIDE + POFF) * WPI + (x * STRIDE + POFF);
        size_t o = ((size_t)(b * CBI + KB0) * PIXPI + p0) * 32 + (lane >> 4) * 8;
        ph[g] = Ah + o;
        pl[g] = Al + o;
    }
    const f16* pw = Wt + (size_t)(by * NOC) * (KPT * 512) + lane * 8;

    int lk = 0, lkx = 0;
    auto advance = [&]() {
#pragma unroll
        for (int g = 0; g < NG; ++g) { ph[g] += (size_t)PIXPI * 32; pl[g] += (size_t)PIXPI * 32; }
        pw += 512;
        if (++lk == KPT) {
            lk = 0;
            int shift = 1;
            if (++lkx == KW) { lkx = 0; shift = WPI - (KW - 1); }
            const long ad = (long)shift * 32 - (long)KPT * PIXPI * 32;
#pragma unroll
            for (int g = 0; g < NG; ++g) { ph[g] += ad; pl[g] += ad; }
            pw += (size_t)(OCB - 1) * (KPT * 512);
        }
    };

    half8 bh[D][NG], bl[D][NG], bw[D][NOC];
    f32x4 acc[NG][NOC] = {};
    f32x4 acc2[NG][NOC] = {};

#pragma unroll
    for (int s = 0; s < D - 1; ++s) {
#pragma unroll
        for (int g = 0; g < NG; ++g) {
            bh[s][g] = *(const half8*)ph[g];
            bl[s][g] = *(const half8*)pl[g];
        }
#pragma unroll
        for (int j = 0; j < NOC; ++j)
            bw[s][j] = *(const half8*)(pw + (size_t)j * (KPT * 512));
        advance();
    }

#pragma unroll 1
    for (int ii = 0; ii < NSTEP / D; ++ii) {
#pragma unroll
        for (int d = 0; d < D; ++d) {
            const int ls = (d + D - 1) % D;
#pragma unroll
            for (int g = 0; g < NG; ++g) {
                bh[ls][g] = *(const half8*)ph[g];
                bl[ls][g] = *(const half8*)pl[g];
            }
#pragma unroll
            for (int j = 0; j < NOC; ++j)
                bw[ls][j] = *(const half8*)(pw + (size_t)j * (KPT * 512));
            advance();
#pragma unroll
            for (int j = 0; j < NOC; ++j)
#pragma unroll
                for (int g = 0; g < NG; ++g) {
                    acc[g][j]  = __builtin_amdgcn_mfma_f32_16x16x32_f16(bh[d][g], bw[d][j], acc[g][j], 0, 0, 0);
                    acc2[g][j] = __builtin_amdgcn_mfma_f32_16x16x32_f16(bl[d][g], bw[d][j], acc2[g][j], 0, 0, 0);
                }
        }
    }

    constexpr int Cc = (MODE == 0) ? (OC >> 1) : OC;
#pragma unroll
    for (int g = 0; g < NG; ++g) {
#pragma unroll
        for (int j = 0; j < NOC; ++j) {
            const int oc = ocbase + j * 16 + (lane & 15);
            const float bv = bias[oc];
#pragma unroll
            for (int r = 0; r < 4; ++r) {
                const int pix = pixbase + 16 * g + ((lane >> 4) << 2) + r;
                const int y = pix >> WSH, x = pix & (WOUT - 1);
                const int pr = (y + 2) * WPI + (x + 2);
                const int pwr = (y + 2) * WPO + (x + 2);
                const size_t pz = (size_t)b * HWOUT + pix;
                float a = acc[g][j][r] + acc2[g][j][r] * (1.0f / 4096.0f) + bv;
                if (MODE == 0) {
                    float s = sigmoid_f(a);
                    if (oc < Cc) {
                        zout[pz * Cc + oc] = s;
                    } else {
                        int hch = oc - Cc;
                        size_t hidx = ((size_t)(b * CBI + (hch >> 5)) * PIXPI + pr) * 32 + (hch & 31);
                        float hv = (float)Ah[hidx] + (float)Al[hidx] * (1.0f / 4096.0f);
                        float rh = s * hv;
                        f16 hi, lo; splitf(rh, hi, lo);
                        int wch = Cc + oc;  // = 2C + (oc-C)
                        size_t widx = ((size_t)(b * CBO + (wch >> 5)) * PIXPO + pwr) * 32 + (wch & 31);
                        Oh[widx] = hi; Ol[widx] = lo;
                    }
                } else if (MODE == 1) {
                    size_t hidx = ((size_t)(b * CBI + (oc >> 5)) * PIXPI + pr) * 32 + (oc & 31);
                    float hv = (float)Ah[hidx] + (float)Al[hidx] * (1.0f / 4096.0f);
                    float zv = zbuf[pz * Cc + oc];
                    float hn = (1.f - zv) * hv + zv * tanhf(a);
                    f16 hi, lo; splitf(hn, hi, lo);
                    Oh[hidx] = hi; Ol[hidx] = lo;
                } else {
                    f16 hi, lo; splitf(a, hi, lo);
                    int wch = OCH0 + oc;
                    size_t widx = ((size_t)(b * CBO + (wch >> 5)) * PIXPO + pwr) * 32 + (wch & 31);
                    Oh[widx] = hi; Ol[widx] = lo;
                }
            }
        }
    }
}

// ---------------------------------------------------------------------------
// conv1 body: IC=1, k4 s2 p1, 128x128 -> 64x64, OC=64, fp32 direct; writes f16
// hi/lo into blocked cat1 xt region (ch [64,128), cblk 2..3, halo 2).
// ---------------------------------------------------------------------------
static __device__ __forceinline__ void conv1_body(
    int bx, int b,
    const float* __restrict__ in, const float* __restrict__ w,
    const float* __restrict__ bias, f16* Oh, f16* Ol)
{
    const int tid = threadIdx.x;
    const int px  = bx * 64 + (tid & 63);
    const int ocg = tid >> 6;
    const int y = px >> 6, x = px & 63;
    const float* src = in + (size_t)b * 196608;
    float v[16];
#pragma unroll
    for (int ky = 0; ky < 4; ++ky)
#pragma unroll
        for (int kx = 0; kx < 4; ++kx) {
            int iy = 2 * y - 1 + ky, ix = 2 * x - 1 + kx;
            v[ky * 4 + kx] = ((unsigned)iy < 128u && (unsigned)ix < 128u) ? src[iy * 128 + ix] : 0.f;
        }
    const int p = (y + 2) * 68 + (x + 2);
#pragma unroll
    for (int o = 0; o < 16; ++o) {
        int ch = 64 + ocg * 16 + o;
        float s = bias[ch - 64];
        const float* wr = w + (ch - 64) * 16;
#pragma unroll
        for (int t = 0; t < 16; ++t) s += wr[t] * v[t];
        f16 hi, lo; splitf(s, hi, lo);
        size_t idx = ((size_t)(b * 6 + (ch >> 5)) * 4624 + p) * 32 + (ch & 31);
        Oh[idx] = hi; Ol[idx] = lo;
    }
}

// ---------------------------------------------------------------------------
// Horizontally-fused pipeline phases.  GRU wavefront: stage1@t, stage2@t-1,
// stage3@t-2 are independent -> fuse each sub-phase across stages.
// Branch order = heaviest work-per-block first (LPT).
// ---------------------------------------------------------------------------

// L1: c2(t-1) [256] | c3(t-2) [128] | conv1(t) [512]  -> 896 blocks
__global__ __launch_bounds__(256) void fused_L1(
    const float* __restrict__ input, const float* __restrict__ c1w, const float* __restrict__ c1b,
    f16* cat1h, f16* cat1l,
    const f16* __restrict__ wt_c2, const float* __restrict__ c2b, f16* cat2h, f16* cat2l,
    const f16* __restrict__ wt_c3, const float* __restrict__ c3b, f16* cat3h, f16* cat3l,
    int t1, int a2, int a3)
{
    const int lin = blockIdx.x;
    if (lin < 256) {
        if (!a2) return;
        gemm_conv_body<4, 4, 2, 2, 1, 4, 4, 6, 0, 68, 4624, 5, 1024, 128, 2, 1, 12, 128, 36, 1296>(
            lin & 15, (lin >> 4) & 1, lin >> 5,
            cat1h, cat1l, wt_c2, c2b, nullptr, nullptr, cat2h, cat2l);
    } else if (lin < 384) {
        if (!a3) return;
        const int l = lin - 256;
        gemm_conv_body<4, 4, 4, 2, 1, 2, 4, 12, 0, 36, 1296, 4, 256, 128, 2, 1, 12, 128, 20, 400>(
            l & 3, (l >> 2) & 3, l >> 4,
            cat2h, cat2l, wt_c3, c3b, nullptr, nullptr, cat3h, cat3l);
    } else {
        if (t1 < 0) return;
        const int l = lin - 384;
        conv1_body(l & 63, l >> 6, input + (size_t)t1 * 16384, c1w, c1b, cat1h, cat1l);
    }
}

// L2: g1zr(t) [512] | g2zr(t-1) [512] | g3zr(t-2) [256]  -> 1280 blocks
__global__ __launch_bounds__(256) void fused_L2(
    f16* cat1h, f16* cat1l, const f16* __restrict__ wt_g1zr, const float* __restrict__ g1zrb, float* z1,
    f16* cat2h, f16* cat2l, const f16* __restrict__ wt_g2zr, const float* __restrict__ g2zrb, float* z2,
    f16* cat3h, f16* cat3l, const f16* __restrict__ wt_g3zr, const float* __restrict__ g3zrb, float* z3,
    int a1, int a2, int a3)
{
    const int lin = blockIdx.x;
    if (lin < 512) {
        if (!a1) return;
        gemm_conv_body<5, 5, 4, 0, 2, 4, 2, 6, 0, 68, 4624, 6, 4096, 128, 1, 0, 6, 0, 68, 4624>(
            lin & 31, (lin >> 5) & 1, lin >> 6,
            cat1h, cat1l, wt_g1zr, g1zrb, nullptr, z1, cat1h, cat1l);
    } else if (lin < 1024) {
        if (!a2) return;
        const int l = lin - 512;
        gemm_conv_body<5, 5, 8, 0, 1, 4, 4, 12, 0, 36, 1296, 5, 1024, 256, 1, 0, 12, 0, 36, 1296>(
            l & 15, (l >> 4) & 3, l >> 6,
            cat2h, cat2l, wt_g2zr, g2zrb, nullptr, z2, cat2h, cat2l);
    } else {
        if (!a3) return;
        const int l = lin - 1024;
        gemm_conv_body<5, 5, 8, 0, 1, 2, 4, 12, 0, 20, 400, 4, 256, 256, 1, 0, 12, 0, 20, 400>(
            l & 3, (l >> 2) & 7, l >> 5,
            cat3h, cat3l, wt_g3zr, g3zrb, nullptr, z3, cat3h, cat3l);
    }
}

// L3: g2h(t-1) [256] | g1h(t) [512] | g3h(t-2) [128]  -> 896 blocks
__global__ __launch_bounds__(256) void fused_L3(
    f16* cat1h, f16* cat1l, const f16* __restrict__ wt_g1h, const float* __restrict__ g1hb, const float* z1,
    f16* cat2h, f16* cat2l, const f16* __restrict__ wt_g2h, const float* __restrict__ g2hb, const float* z2,
    f16* cat3h, f16* cat3l, const f16* __restrict__ wt_g3h, const float* __restrict__ g3hb, const float* z3,
    int a1, int a2, int a3)
{
    const int lin = blockIdx.x;
    if (lin < 256) {
        if (!a2) return;
        gemm_conv_body<5, 5, 8, 1, 1, 4, 4, 12, 4, 36, 1296, 5, 1024, 128, 1, 0, 12, 0, 36, 1296>(
            lin & 15, (lin >> 4) & 1, lin >> 5,
            cat2h, cat2l, wt_g2h, g2hb, z2, nullptr, cat2h, cat2l);
    } else if (lin < 768) {
        if (!a1) return;
        const int l = lin - 256;
        gemm_conv_body<5, 5, 4, 1, 1, 4, 4, 6, 2, 68, 4624, 6, 4096, 64, 1, 0, 6, 0, 68, 4624>(
            l & 63, 0, l >> 6,
            cat1h, cat1l, wt_g1h, g1hb, z1, nullptr, cat1h, cat1l);
    } else {
        if (!a3) return;
        const int l = lin - 768;
        gemm_conv_body<5, 5, 8, 1, 1, 2, 4, 12, 4, 20, 400, 4, 256, 128, 1, 0, 12, 0, 20, 400>(
            l & 3, (l >> 2) & 3, l >> 4,
            cat3h, cat3l, wt_g3h, g3hb, z3, nullptr, cat3h, cat3l);
    }
}

// w[oc][ic][kh][kw] fp32 -> blocked f16 [tap][ocblk][kblk][kgrp4][oc16][ch8].
// perm=1: swap input-channel halves (zr convs: ref concat [x,h] -> cat [h,xt]).
__global__ __launch_bounds__(256) void prep_w(
    const float* __restrict__ w, f16* __restrict__ wt,
    int OC, int IC, int KK, int perm)
{
    int i = blockIdx.x * 256 + threadIdx.x;
    int total = OC * IC * KK;
    if (i >= total) return;
    int oc = i / (IC * KK);
    int r  = i - oc * (IC * KK);
    int ic = r / KK;
    int tap = r - ic * KK;
    int icn = perm ? ((ic < IC / 2) ? ic + IC / 2 : ic - IC / 2) : ic;
    int OCB = OC >> 4, KPT = IC >> 5;
    int ob = oc >> 4, ol = oc & 15;
    int kb = icn >> 5, kg = (icn >> 3) & 3, ch = icn & 7;
    size_t o = (((size_t)tap * OCB + ob) * KPT + kb) * 512 + kg * 128 + ol * 8 + ch;
    wt[o] = (f16)w[i];
}

// blocked cat hi/lo h-region -> fp32 NCHW
__global__ __launch_bounds__(256) void cat_to_nchw(
    const f16* __restrict__ hi, const f16* __restrict__ lo,
    float* __restrict__ dst, int C, int HW, int wsh, int WP, int PIXP, int CB)
{
    int i = blockIdx.x * 256 + threadIdx.x;
    int b = i / (C * HW);
    int r = i - b * (C * HW);
    int c = r / HW;
    int p = r - c * HW;
    int y = p >> wsh, x = p & ((1 << wsh) - 1);
    size_t s = ((size_t)(b * CB + (c >> 5)) * PIXP + (size_t)(y + 2) * WP + (x + 2)) * 32 + (c & 31);
    dst[i] = (float)hi[s] + (float)lo[s] * (1.0f / 4096.0f);
}

// ---------------------------------------------------------------------------
extern "C" void kernel_launch(void* const* d_in, const int* in_sizes, int n_in,
                              void* d_out, int out_size, void* d_ws, size_t ws_size,
                              hipStream_t stream)
{
    (void)in_sizes; (void)n_in; (void)out_size; (void)ws_size;

    const float* input  = (const float*)d_in[0];
    const float* c1_w   = (const float*)d_in[1];
    const float* c1_b   = (const float*)d_in[2];
    const float* g1zr_w = (const float*)d_in[3];
    const float* g1zr_b = (const float*)d_in[4];
    const float* g1h_w  = (const float*)d_in[5];
    const float* g1h_b  = (const float*)d_in[6];
    const float* c2_w   = (const float*)d_in[7];
    const float* c2_b   = (const float*)d_in[8];
    const float* g2zr_w = (const float*)d_in[9];
    const float* g2zr_b = (const float*)d_in[10];
    const float* g2h_w  = (const float*)d_in[11];
    const float* g2h_b  = (const float*)d_in[12];
    const float* c3_w   = (const float*)d_in[13];
    const float* c3_b   = (const float*)d_in[14];
    const float* g3zr_w = (const float*)d_in[15];
    const float* g3zr_b = (const float*)d_in[16];
    const float* g3h_w  = (const float*)d_in[17];
    const float* g3h_b  = (const float*)d_in[18];

    float* out1 = (float*)d_out;                 // [8,64,64,64]  NCHW
    float* out2 = (float*)d_out + 2097152;       // [8,128,32,32]
    float* out3 = (float*)d_out + 3145728;       // [8,128,16,16]

    char* ws = (char*)d_ws;
    size_t off = 0;
    auto takeB = [&](size_t bytes) { char* p = ws + off; off += (bytes + 255) & ~(size_t)255; return p; };

    const size_t WSLACK = 400000;
    f16* wt_g1zr = (f16*)takeB((size_t)25 * 128 * 128 * 2 + WSLACK);
    f16* wt_g1h  = (f16*)takeB((size_t)25 * 64 * 128 * 2 + WSLACK);
    f16* wt_c2   = (f16*)takeB((size_t)16 * 128 * 64 * 2 + WSLACK);
    f16* wt_g2zr = (f16*)takeB((size_t)25 * 256 * 256 * 2 + WSLACK);
    f16* wt_g2h  = (f16*)takeB((size_t)25 * 128 * 256 * 2 + WSLACK);
    f16* wt_c3   = (f16*)takeB((size_t)16 * 128 * 128 * 2 + WSLACK);
    f16* wt_g3zr = (f16*)takeB((size_t)25 * 256 * 256 * 2 + WSLACK);
    f16* wt_g3h  = (f16*)takeB((size_t)25 * 128 * 256 * 2 + WSLACK);

    // blocked padded cat buffers: [b][cblk][pixP][32], hi/lo planes
    const size_t cat1_n = (size_t)8 * 6 * 4624 * 32;   // 68x68, 192ch
    const size_t cat2_n = (size_t)8 * 12 * 1296 * 32;  // 36x36, 384ch
    const size_t cat3_n = (size_t)8 * 12 * 400 * 32;   // 20x20, 384ch
    const size_t ASLACK = 1 << 20;
    f16* cat1h = (f16*)takeB(cat1_n * 2 + ASLACK);
    f16* cat1l = (f16*)takeB(cat1_n * 2 + ASLACK);
    f16* cat2h = (f16*)takeB(cat2_n * 2 + ASLACK);
    f16* cat2l = (f16*)takeB(cat2_n * 2 + ASLACK);
    f16* cat3h = (f16*)takeB(cat3_n * 2 + ASLACK);
    f16* cat3l = (f16*)takeB(cat3_n * 2 + ASLACK);
    float* z1 = (float*)takeB((size_t)8 * 4096 * 64 * 4);
    float* z2 = (float*)takeB((size_t)8 * 1024 * 128 * 4);
    float* z3 = (float*)takeB((size_t)8 * 256 * 128 * 4);

    hipMemsetAsync(cat1h, 0, cat1_n * 2, stream);
    hipMemsetAsync(cat1l, 0, cat1_n * 2, stream);
    hipMemsetAsync(cat2h, 0, cat2_n * 2, stream);
    hipMemsetAsync(cat2l, 0, cat2_n * 2, stream);
    hipMemsetAsync(cat3h, 0, cat3_n * 2, stream);
    hipMemsetAsync(cat3l, 0, cat3_n * 2, stream);

    auto prep = [&](const float* w, f16* wt, int OC, int IC, int KK, int perm) {
        int total = OC * IC * KK;
        prep_w<<<(total + 255) / 256, 256, 0, stream>>>(w, wt, OC, IC, KK, perm);
    };
    prep(g1zr_w, wt_g1zr, 128, 128, 25, 1);
    prep(g1h_w,  wt_g1h,  64, 128, 25, 0);
    prep(c2_w,   wt_c2,   128, 64, 16, 0);
    prep(g2zr_w, wt_g2zr, 256, 256, 25, 1);
    prep(g2h_w,  wt_g2h,  128, 256, 25, 0);
    prep(c3_w,   wt_c3,   128, 128, 16, 0);
    prep(g3zr_w, wt_g3zr, 256, 256, 25, 1);
    prep(g3h_w,  wt_g3h,  128, 256, 25, 0);

    // Software-pipelined wavefront: iteration i runs stage1@t=i, stage2@t=i-1,
    // stage3@t=i-2.  12 steps -> 14 iterations (2 fill, 2 drain).
    for (int i = 0; i < 14; ++i) {
        const int t1 = (i < 12) ? i : -1;
        const int a1 = (i < 12) ? 1 : 0;
        const int a2 = (i >= 1 && i <= 12) ? 1 : 0;
        const int a3 = (i >= 2) ? 1 : 0;

        fused_L1<<<896, 256, 0, stream>>>(
            input, c1_w, c1_b, cat1h, cat1l,
            wt_c2, c2_b, cat2h, cat2l,
            wt_c3, c3_b, cat3h, cat3l,
            t1, a2, a3);
        fused_L2<<<1280, 256, 0, stream>>>(
            cat1h, cat1l, wt_g1zr, g1zr_b, z1,
            cat2h, cat2l, wt_g2zr, g2zr_b, z2,
            cat3h, cat3l, wt_g3zr, g3zr_b, z3,
            a1, a2, a3);
        fused_L3<<<896, 256, 0, stream>>>(
            cat1h, cat1l, wt_g1h, g1h_b, z1,
            cat2h, cat2l, wt_g2h, g2h_b, z2,
            cat3h, cat3l, wt_g3h, g3h_b, z3,
            a1, a2, a3);
    }

    cat_to_nchw<<<8192, 256, 0, stream>>>(cat1h, cat1l, out1, 64, 4096, 6, 68, 4624, 6);
    cat_to_nchw<<<4096, 256, 0, stream>>>(cat2h, cat2l, out2, 128, 1024, 5, 36, 1296, 12);
    cat_to_nchw<<<1024, 256, 0, stream>>>(cat3h, cat3l, out3, 128, 256, 4, 20, 400, 12);
}

// Round 2
// 4133.454 us; speedup vs baseline: 1.2960x; 1.2285x over previous
//
#include <hip/hip_runtime.h>
#include <math.h>

typedef _Float16 f16;
typedef __attribute__((ext_vector_type(8))) _Float16 half8;
typedef __attribute__((ext_vector_type(4))) float f32x4;

static __device__ __forceinline__ float sigmoid_f(float x) { return 1.0f / (1.0f + expf(-x)); }

// exact split: x == (float)hi + (float)lo / 4096 (lo pre-scaled to dodge denormals)
static __device__ __forceinline__ void splitf(float x, f16& hi, f16& lo) {
    hi = (f16)x;
    float r = x - (float)hi;
    lo = (f16)(r * 4096.0f);
}

// ---------------------------------------------------------------------------
// Tap-decomposed implicit-GEMM conv, f16 MFMA, 2-term activation split,
// fp32 accumulate.  R2 change: kernel was L2-BW-bound at ~22 TB/s with the
// B (weight) stream fetched redundantly by all 4 waves of a block (identical
// ocbase).  B is now staged in LDS once per block, double-buffered in groups
// of STG=4 steps.  Reg-staged (global->reg, ds_write late) so the compiler's
// per-register vmcnt keeps it correct; raw s_barrier + lgkmcnt(0) only, so
// the A global-load pipeline is NEVER drained at group boundaries.
//   A-frag: lane&15=pixel, k=(lane>>4)*8+j ; B-frag: lane&15=oc, same k.
//   D-frag: col(oc)=lane&15, row(pixel)=(lane>>4)*4+reg  [HW-verified]
// ---------------------------------------------------------------------------
template <int KH, int KW, int KPT, int MODE, int NG, int NOC, int D,
          int CBI, int KB0, int WPI, int PIXPI,
          int WSH, int HWOUT, int OC, int STRIDE, int POFF,
          int CBO, int OCH0, int WPO, int PIXPO>
static __device__ __forceinline__ void gemm_conv_body(
    int bx, int by, int b,
    const f16* Ah, const f16* Al, const f16* __restrict__ Wt,
    const float* __restrict__ bias, const float* __restrict__ zbuf,
    float* zout, f16* Oh, f16* Ol, f16* smem)
{
    constexpr int NSTEP = KH * KW * KPT;
    constexpr int WOUT  = 1 << WSH;
    constexpr int OCB   = OC / 16;
    constexpr int STG   = 4;               // steps per LDS stage group
    constexpr int NGRP  = NSTEP / STG;
    constexpr int PPW   = (STG * NOC) / 4; // staged 1KB pieces per wave
    static_assert(NSTEP % STG == 0, "NSTEP divisible by STG");
    static_assert(STG % D == 0, "D must divide STG");
    static_assert(NOC == 2 || NOC == 4, "NOC in {2,4}");

    const int lane = threadIdx.x & 63;
    const int wave = threadIdx.x >> 6;
    const int pixbase = (bx * 4 + wave) * (NG * 16);
    const int ocbase  = by * (NOC * 16);

    const f16* ph[NG];
    const f16* pl[NG];
#pragma unroll
    for (int g = 0; g < NG; ++g) {
        int apix = pixbase + 16 * g + (lane & 15);
        int y = apix >> WSH, x = apix & (WOUT - 1);
        int p0 = (y * STRIDE + POFF) * WPI + (x * STRIDE + POFF);
        size_t o = ((size_t)(b * CBI + KB0) * PIXPI + p0) * 32 + (lane >> 4) * 8;
        ph[g] = Ah + o;
        pl[g] = Al + o;
    }

    int lk = 0, lkx = 0;
    auto advance = [&]() {
#pragma unroll
        for (int g = 0; g < NG; ++g) { ph[g] += (size_t)PIXPI * 32; pl[g] += (size_t)PIXPI * 32; }
        if (++lk == KPT) {
            lk = 0;
            int shift = 1;
            if (++lkx == KW) { lkx = 0; shift = WPI - (KW - 1); }
            const long ad = (long)shift * 32 - (long)KPT * PIXPI * 32;
#pragma unroll
            for (int g = 0; g < NG; ++g) { ph[g] += ad; pl[g] += ad; }
        }
    };

    // B piece (1KB = 512 f16 = [kgrp4][oc16][ch8]) for flat step s, oc-block j
    auto bpiece = [&](int s, int j) -> const f16* {
        int t = s / KPT, kb = s % KPT;   // KPT is a power of 2
        return Wt + (((size_t)(t * OCB + by * NOC + j)) * KPT + kb) * 512;
    };

    half8 stg[PPW];
    auto stage_issue = [&](int g0) {
#pragma unroll
        for (int p = 0; p < PPW; ++p) {
            const int pc = wave * PPW + p;
            const int kk = pc / NOC, j = pc % NOC;
            stg[p] = *(const half8*)(bpiece(g0 * STG + kk, j) + lane * 8);
        }
    };
    auto stage_write = [&](f16* dst) {
#pragma unroll
        for (int p = 0; p < PPW; ++p) {
            const int pc = wave * PPW + p;
            *(half8*)(dst + pc * 512 + lane * 8) = stg[p];
        }
    };

    half8 bh[D][NG], bl[D][NG];
    half8 bwreg[2][NOC];
    f32x4 acc[NG][NOC] = {};
    f32x4 acc2[NG][NOC] = {};

    // prologue: stage group 0 into smem[0]; A pipeline D-1 deep
    stage_issue(0);
    stage_write(smem);
#pragma unroll
    for (int s = 0; s < D - 1; ++s) {
#pragma unroll
        for (int g = 0; g < NG; ++g) {
            bh[s][g] = *(const half8*)ph[g];
            bl[s][g] = *(const half8*)pl[g];
        }
        advance();
    }
    asm volatile("s_waitcnt lgkmcnt(0)" ::: "memory");
    __builtin_amdgcn_s_barrier();
    __builtin_amdgcn_sched_barrier(0);

#pragma unroll 1
    for (int gi = 0; gi < NGRP; ++gi) {
        f16* cur = smem + (gi & 1) * 8192;
        f16* nxt = smem + ((gi & 1) ^ 1) * 8192;
        if (gi + 1 < NGRP) stage_issue(gi + 1);
#pragma unroll
        for (int j = 0; j < NOC; ++j)
            bwreg[0][j] = *(const half8*)(cur + j * 512 + lane * 8);
#pragma unroll
        for (int kk = 0; kk < STG; ++kk) {
            if (kk + 1 < STG) {
#pragma unroll
                for (int j = 0; j < NOC; ++j)
                    bwreg[(kk + 1) & 1][j] = *(const half8*)(cur + ((kk + 1) * NOC + j) * 512 + lane * 8);
            }
            const int ls = (kk + D - 1) % D;
#pragma unroll
            for (int g = 0; g < NG; ++g) {
                bh[ls][g] = *(const half8*)ph[g];
                bl[ls][g] = *(const half8*)pl[g];
            }
            advance();
            const int dd = kk % D;
#pragma unroll
            for (int j = 0; j < NOC; ++j)
#pragma unroll
                for (int g = 0; g < NG; ++g) {
                    acc[g][j]  = __builtin_amdgcn_mfma_f32_16x16x32_f16(bh[dd][g], bwreg[kk & 1][j], acc[g][j], 0, 0, 0);
                    acc2[g][j] = __builtin_amdgcn_mfma_f32_16x16x32_f16(bl[dd][g], bwreg[kk & 1][j], acc2[g][j], 0, 0, 0);
                }
        }
        if (gi + 1 < NGRP) {
            stage_write(nxt);
            asm volatile("s_waitcnt lgkmcnt(0)" ::: "memory");
            __builtin_amdgcn_s_barrier();
            __builtin_amdgcn_sched_barrier(0);
        }
    }

    constexpr int Cc = (MODE == 0) ? (OC >> 1) : OC;
#pragma unroll
    for (int g = 0; g < NG; ++g) {
#pragma unroll
        for (int j = 0; j < NOC; ++j) {
            const int oc = ocbase + j * 16 + (lane & 15);
            const float bv = bias[oc];
#pragma unroll
            for (int r = 0; r < 4; ++r) {
                const int pix = pixbase + 16 * g + ((lane >> 4) << 2) + r;
                const int y = pix >> WSH, x = pix & (WOUT - 1);
                const int pr = (y + 2) * WPI + (x + 2);
                const int pwr = (y + 2) * WPO + (x + 2);
                const size_t pz = (size_t)b * HWOUT + pix;
                float a = acc[g][j][r] + acc2[g][j][r] * (1.0f / 4096.0f) + bv;
                if (MODE == 0) {
                    float s = sigmoid_f(a);
                    if (oc < Cc) {
                        zout[pz * Cc + oc] = s;
                    } else {
                        int hch = oc - Cc;
                        size_t hidx = ((size_t)(b * CBI + (hch >> 5)) * PIXPI + pr) * 32 + (hch & 31);
                        float hv = (float)Ah[hidx] + (float)Al[hidx] * (1.0f / 4096.0f);
                        float rh = s * hv;
                        f16 hi, lo; splitf(rh, hi, lo);
                        int wch = Cc + oc;  // = 2C + (oc-C)
                        size_t widx = ((size_t)(b * CBO + (wch >> 5)) * PIXPO + pwr) * 32 + (wch & 31);
                        Oh[widx] = hi; Ol[widx] = lo;
                    }
                } else if (MODE == 1) {
                    size_t hidx = ((size_t)(b * CBI + (oc >> 5)) * PIXPI + pr) * 32 + (oc & 31);
                    float hv = (float)Ah[hidx] + (float)Al[hidx] * (1.0f / 4096.0f);
                    float zv = zbuf[pz * Cc + oc];
                    float hn = (1.f - zv) * hv + zv * tanhf(a);
                    f16 hi, lo; splitf(hn, hi, lo);
                    Oh[hidx] = hi; Ol[hidx] = lo;
                } else {
                    f16 hi, lo; splitf(a, hi, lo);
                    int wch = OCH0 + oc;
                    size_t widx = ((size_t)(b * CBO + (wch >> 5)) * PIXPO + pwr) * 32 + (wch & 31);
                    Oh[widx] = hi; Ol[widx] = lo;
                }
            }
        }
    }
}

// ---------------------------------------------------------------------------
// conv1 body: IC=1, k4 s2 p1, 128x128 -> 64x64, OC=64, fp32 direct; writes f16
// hi/lo into blocked cat1 xt region (ch [64,128), cblk 2..3, halo 2).
// ---------------------------------------------------------------------------
static __device__ __forceinline__ void conv1_body(
    int bx, int b,
    const float* __restrict__ in, const float* __restrict__ w,
    const float* __restrict__ bias, f16* Oh, f16* Ol)
{
    const int tid = threadIdx.x;
    const int px  = bx * 64 + (tid & 63);
    const int ocg = tid >> 6;
    const int y = px >> 6, x = px & 63;
    const float* src = in + (size_t)b * 196608;
    float v[16];
#pragma unroll
    for (int ky = 0; ky < 4; ++ky)
#pragma unroll
        for (int kx = 0; kx < 4; ++kx) {
            int iy = 2 * y - 1 + ky, ix = 2 * x - 1 + kx;
            v[ky * 4 + kx] = ((unsigned)iy < 128u && (unsigned)ix < 128u) ? src[iy * 128 + ix] : 0.f;
        }
    const int p = (y + 2) * 68 + (x + 2);
#pragma unroll
    for (int o = 0; o < 16; ++o) {
        int ch = 64 + ocg * 16 + o;
        float s = bias[ch - 64];
        const float* wr = w + (ch - 64) * 16;
#pragma unroll
        for (int t = 0; t < 16; ++t) s += wr[t] * v[t];
        f16 hi, lo; splitf(s, hi, lo);
        size_t idx = ((size_t)(b * 6 + (ch >> 5)) * 4624 + p) * 32 + (ch & 31);
        Oh[idx] = hi; Ol[idx] = lo;
    }
}

// ---------------------------------------------------------------------------
// Horizontally-fused pipeline phases.  GRU wavefront: stage1@t, stage2@t-1,
// stage3@t-2 are independent -> fuse each sub-phase across stages.
// ---------------------------------------------------------------------------

// L1: c2(t-1) [256] | c3(t-2) [128] | conv1(t) [512]  -> 896 blocks
__global__ __launch_bounds__(256) void fused_L1(
    const float* __restrict__ input, const float* __restrict__ c1w, const float* __restrict__ c1b,
    f16* cat1h, f16* cat1l,
    const f16* __restrict__ wt_c2, const float* __restrict__ c2b, f16* cat2h, f16* cat2l,
    const f16* __restrict__ wt_c3, const float* __restrict__ c3b, f16* cat3h, f16* cat3l,
    int t1, int a2, int a3)
{
    __shared__ f16 smem[2 * 8192];
    const int lin = blockIdx.x;
    if (lin < 256) {
        if (!a2) return;
        gemm_conv_body<4, 4, 2, 2, 1, 4, 4, 6, 0, 68, 4624, 5, 1024, 128, 2, 1, 12, 128, 36, 1296>(
            lin & 15, (lin >> 4) & 1, lin >> 5,
            cat1h, cat1l, wt_c2, c2b, nullptr, nullptr, cat2h, cat2l, smem);
    } else if (lin < 384) {
        if (!a3) return;
        const int l = lin - 256;
        gemm_conv_body<4, 4, 4, 2, 1, 2, 4, 12, 0, 36, 1296, 4, 256, 128, 2, 1, 12, 128, 20, 400>(
            l & 3, (l >> 2) & 3, l >> 4,
            cat2h, cat2l, wt_c3, c3b, nullptr, nullptr, cat3h, cat3l, smem);
    } else {
        if (t1 < 0) return;
        const int l = lin - 384;
        conv1_body(l & 63, l >> 6, input + (size_t)t1 * 16384, c1w, c1b, cat1h, cat1l);
    }
}

// L2: g1zr(t) [512] | g2zr(t-1) [512] | g3zr(t-2) [256]  -> 1280 blocks
__global__ __launch_bounds__(256) void fused_L2(
    f16* cat1h, f16* cat1l, const f16* __restrict__ wt_g1zr, const float* __restrict__ g1zrb, float* z1,
    f16* cat2h, f16* cat2l, const f16* __restrict__ wt_g2zr, const float* __restrict__ g2zrb, float* z2,
    f16* cat3h, f16* cat3l, const f16* __restrict__ wt_g3zr, const float* __restrict__ g3zrb, float* z3,
    int a1, int a2, int a3)
{
    __shared__ f16 smem[2 * 8192];
    const int lin = blockIdx.x;
    if (lin < 512) {
        if (!a1) return;
        gemm_conv_body<5, 5, 4, 0, 2, 4, 2, 6, 0, 68, 4624, 6, 4096, 128, 1, 0, 6, 0, 68, 4624>(
            lin & 31, (lin >> 5) & 1, lin >> 6,
            cat1h, cat1l, wt_g1zr, g1zrb, nullptr, z1, cat1h, cat1l, smem);
    } else if (lin < 1024) {
        if (!a2) return;
        const int l = lin - 512;
        gemm_conv_body<5, 5, 8, 0, 1, 4, 4, 12, 0, 36, 1296, 5, 1024, 256, 1, 0, 12, 0, 36, 1296>(
            l & 15, (l >> 4) & 3, l >> 6,
            cat2h, cat2l, wt_g2zr, g2zrb, nullptr, z2, cat2h, cat2l, smem);
    } else {
        if (!a3) return;
        const int l = lin - 1024;
        gemm_conv_body<5, 5, 8, 0, 1, 2, 4, 12, 0, 20, 400, 4, 256, 256, 1, 0, 12, 0, 20, 400>(
            l & 3, (l >> 2) & 7, l >> 5,
            cat3h, cat3l, wt_g3zr, g3zrb, nullptr, z3, cat3h, cat3l, smem);
    }
}

// L3: g2h(t-1) [256] | g1h(t) [512] | g3h(t-2) [128]  -> 896 blocks
__global__ __launch_bounds__(256) void fused_L3(
    f16* cat1h, f16* cat1l, const f16* __restrict__ wt_g1h, const float* __restrict__ g1hb, const float* z1,
    f16* cat2h, f16* cat2l, const f16* __restrict__ wt_g2h, const float* __restrict__ g2hb, const float* z2,
    f16* cat3h, f16* cat3l, const f16* __restrict__ wt_g3h, const float* __restrict__ g3hb, const float* z3,
    int a1, int a2, int a3)
{
    __shared__ f16 smem[2 * 8192];
    const int lin = blockIdx.x;
    if (lin < 256) {
        if (!a2) return;
        gemm_conv_body<5, 5, 8, 1, 1, 4, 4, 12, 4, 36, 1296, 5, 1024, 128, 1, 0, 12, 0, 36, 1296>(
            lin & 15, (lin >> 4) & 1, lin >> 5,
            cat2h, cat2l, wt_g2h, g2hb, z2, nullptr, cat2h, cat2l, smem);
    } else if (lin < 768) {
        if (!a1) return;
        const int l = lin - 256;
        gemm_conv_body<5, 5, 4, 1, 1, 4, 4, 6, 2, 68, 4624, 6, 4096, 64, 1, 0, 6, 0, 68, 4624>(
            l & 63, 0, l >> 6,
            cat1h, cat1l, wt_g1h, g1hb, z1, nullptr, cat1h, cat1l, smem);
    } else {
        if (!a3) return;
        const int l = lin - 768;
        gemm_conv_body<5, 5, 8, 1, 1, 2, 4, 12, 4, 20, 400, 4, 256, 128, 1, 0, 12, 0, 20, 400>(
            l & 3, (l >> 2) & 3, l >> 4,
            cat3h, cat3l, wt_g3h, g3hb, z3, nullptr, cat3h, cat3l, smem);
    }
}

// w[oc][ic][kh][kw] fp32 -> blocked f16 [tap][ocblk][kblk][kgrp4][oc16][ch8].
// perm=1: swap input-channel halves (zr convs: ref concat [x,h] -> cat [h,xt]).
__global__ __launch_bounds__(256) void prep_w(
    const float* __restrict__ w, f16* __restrict__ wt,
    int OC, int IC, int KK, int perm)
{
    int i = blockIdx.x * 256 + threadIdx.x;
    int total = OC * IC * KK;
    if (i >= total) return;
    int oc = i / (IC * KK);
    int r  = i - oc * (IC * KK);
    int ic = r / KK;
    int tap = r - ic * KK;
    int icn = perm ? ((ic < IC / 2) ? ic + IC / 2 : ic - IC / 2) : ic;
    int OCB = OC >> 4, KPT = IC >> 5;
    int ob = oc >> 4, ol = oc & 15;
    int kb = icn >> 5, kg = (icn >> 3) & 3, ch = icn & 7;
    size_t o = (((size_t)tap * OCB + ob) * KPT + kb) * 512 + kg * 128 + ol * 8 + ch;
    wt[o] = (f16)w[i];
}

// blocked cat hi/lo h-region -> fp32 NCHW
__global__ __launch_bounds__(256) void cat_to_nchw(
    const f16* __restrict__ hi, const f16* __restrict__ lo,
    float* __restrict__ dst, int C, int HW, int wsh, int WP, int PIXP, int CB)
{
    int i = blockIdx.x * 256 + threadIdx.x;
    int b = i / (C * HW);
    int r = i - b * (C * HW);
    int c = r / HW;
    int p = r - c * HW;
    int y = p >> wsh, x = p & ((1 << wsh) - 1);
    size_t s = ((size_t)(b * CB + (c >> 5)) * PIXP + (size_t)(y + 2) * WP + (x + 2)) * 32 + (c & 31);
    dst[i] = (float)hi[s] + (float)lo[s] * (1.0f / 4096.0f);
}

// ---------------------------------------------------------------------------
extern "C" void kernel_launch(void* const* d_in, const int* in_sizes, int n_in,
                              void* d_out, int out_size, void* d_ws, size_t ws_size,
                              hipStream_t stream)
{
    (void)in_sizes; (void)n_in; (void)out_size; (void)ws_size;

    const float* input  = (const float*)d_in[0];
    const float* c1_w   = (const float*)d_in[1];
    const float* c1_b   = (const float*)d_in[2];
    const float* g1zr_w = (const float*)d_in[3];
    const float* g1zr_b = (const float*)d_in[4];
    const float* g1h_w  = (const float*)d_in[5];
    const float* g1h_b  = (const float*)d_in[6];
    const float* c2_w   = (const float*)d_in[7];
    const float* c2_b   = (const float*)d_in[8];
    const float* g2zr_w = (const float*)d_in[9];
    const float* g2zr_b = (const float*)d_in[10];
    const float* g2h_w  = (const float*)d_in[11];
    const float* g2h_b  = (const float*)d_in[12];
    const float* c3_w   = (const float*)d_in[13];
    const float* c3_b   = (const float*)d_in[14];
    const float* g3zr_w = (const float*)d_in[15];
    const float* g3zr_b = (const float*)d_in[16];
    const float* g3h_w  = (const float*)d_in[17];
    const float* g3h_b  = (const float*)d_in[18];

    float* out1 = (float*)d_out;                 // [8,64,64,64]  NCHW
    float* out2 = (float*)d_out + 2097152;       // [8,128,32,32]
    float* out3 = (float*)d_out + 3145728;       // [8,128,16,16]

    char* ws = (char*)d_ws;
    size_t off = 0;
    auto takeB = [&](size_t bytes) { char* p = ws + off; off += (bytes + 255) & ~(size_t)255; return p; };

    const size_t WSLACK = 400000;
    f16* wt_g1zr = (f16*)takeB((size_t)25 * 128 * 128 * 2 + WSLACK);
    f16* wt_g1h  = (f16*)takeB((size_t)25 * 64 * 128 * 2 + WSLACK);
    f16* wt_c2   = (f16*)takeB((size_t)16 * 128 * 64 * 2 + WSLACK);
    f16* wt_g2zr = (f16*)takeB((size_t)25 * 256 * 256 * 2 + WSLACK);
    f16* wt_g2h  = (f16*)takeB((size_t)25 * 128 * 256 * 2 + WSLACK);
    f16* wt_c3   = (f16*)takeB((size_t)16 * 128 * 128 * 2 + WSLACK);
    f16* wt_g3zr = (f16*)takeB((size_t)25 * 256 * 256 * 2 + WSLACK);
    f16* wt_g3h  = (f16*)takeB((size_t)25 * 128 * 256 * 2 + WSLACK);

    // blocked padded cat buffers: [b][cblk][pixP][32], hi/lo planes
    const size_t cat1_n = (size_t)8 * 6 * 4624 * 32;   // 68x68, 192ch
    const size_t cat2_n = (size_t)8 * 12 * 1296 * 32;  // 36x36, 384ch
    const size_t cat3_n = (size_t)8 * 12 * 400 * 32;   // 20x20, 384ch
    const size_t ASLACK = 1 << 20;
    f16* cat1h = (f16*)takeB(cat1_n * 2 + ASLACK);
    f16* cat1l = (f16*)takeB(cat1_n * 2 + ASLACK);
    f16* cat2h = (f16*)takeB(cat2_n * 2 + ASLACK);
    f16* cat2l = (f16*)takeB(cat2_n * 2 + ASLACK);
    f16* cat3h = (f16*)takeB(cat3_n * 2 + ASLACK);
    f16* cat3l = (f16*)takeB(cat3_n * 2 + ASLACK);
    float* z1 = (float*)takeB((size_t)8 * 4096 * 64 * 4);
    float* z2 = (float*)takeB((size_t)8 * 1024 * 128 * 4);
    float* z3 = (float*)takeB((size_t)8 * 256 * 128 * 4);

    hipMemsetAsync(cat1h, 0, cat1_n * 2, stream);
    hipMemsetAsync(cat1l, 0, cat1_n * 2, stream);
    hipMemsetAsync(cat2h, 0, cat2_n * 2, stream);
    hipMemsetAsync(cat2l, 0, cat2_n * 2, stream);
    hipMemsetAsync(cat3h, 0, cat3_n * 2, stream);
    hipMemsetAsync(cat3l, 0, cat3_n * 2, stream);

    auto prep = [&](const float* w, f16* wt, int OC, int IC, int KK, int perm) {
        int total = OC * IC * KK;
        prep_w<<<(total + 255) / 256, 256, 0, stream>>>(w, wt, OC, IC, KK, perm);
    };
    prep(g1zr_w, wt_g1zr, 128, 128, 25, 1);
    prep(g1h_w,  wt_g1h,  64, 128, 25, 0);
    prep(c2_w,   wt_c2,   128, 64, 16, 0);
    prep(g2zr_w, wt_g2zr, 256, 256, 25, 1);
    prep(g2h_w,  wt_g2h,  128, 256, 25, 0);
    prep(c3_w,   wt_c3,   128, 128, 16, 0);
    prep(g3zr_w, wt_g3zr, 256, 256, 25, 1);
    prep(g3h_w,  wt_g3h,  128, 256, 25, 0);

    // Software-pipelined wavefront: iteration i runs stage1@t=i, stage2@t=i-1,
    // stage3@t=i-2.  12 steps -> 14 iterations (2 fill, 2 drain).
    for (int i = 0; i < 14; ++i) {
        const int t1 = (i < 12) ? i : -1;
        const int a1 = (i < 12) ? 1 : 0;
        const int a2 = (i >= 1 && i <= 12) ? 1 : 0;
        const int a3 = (i >= 2) ? 1 : 0;

        fused_L1<<<896, 256, 0, stream>>>(
            input, c1_w, c1_b, cat1h, cat1l,
            wt_c2, c2_b, cat2h, cat2l,
            wt_c3, c3_b, cat3h, cat3l,
            t1, a2, a3);
        fused_L2<<<1280, 256, 0, stream>>>(
            cat1h, cat1l, wt_g1zr, g1zr_b, z1,
            cat2h, cat2l, wt_g2zr, g2zr_b, z2,
            cat3h, cat3l, wt_g3zr, g3zr_b, z3,
            a1, a2, a3);
        fused_L3<<<896, 256, 0, stream>>>(
            cat1h, cat1l, wt_g1h, g1h_b, z1,
            cat2h, cat2l, wt_g2h, g2h_b, z2,
            cat3h, cat3l, wt_g3h, g3h_b, z3,
            a1, a2, a3);
    }

    cat_to_nchw<<<8192, 256, 0, stream>>>(cat1h, cat1l, out1, 64, 4096, 6, 68, 4624, 6);
    cat_to_nchw<<<4096, 256, 0, stream>>>(cat2h, cat2l, out2, 128, 1024, 5, 36, 1296, 12);
    cat_to_nchw<<<1024, 256, 0, stream>>>(cat3h, cat3l, out3, 128, 256, 4, 20, 400, 12);
}

// Round 3
// 3938.737 us; speedup vs baseline: 1.3601x; 1.0494x over previous
//
#include <hip/hip_runtime.h>
#include <math.h>

typedef _Float16 f16;
typedef __attribute__((ext_vector_type(8))) _Float16 half8;
typedef __attribute__((ext_vector_type(4))) float f32x4;

template <int N> struct ic { static constexpr int v = N; };

static __device__ __forceinline__ float sigmoid_f(float x) { return 1.0f / (1.0f + expf(-x)); }

// exact split: x == (float)hi + (float)lo / 4096 (lo pre-scaled to dodge denormals)
static __device__ __forceinline__ void splitf(float x, f16& hi, f16& lo) {
    hi = (f16)x;
    float r = x - (float)hi;
    lo = (f16)(r * 4096.0f);
}

// vmcnt-only s_waitcnt immediate (gfx9 encoding): vm[3:0] | exp[6:4]=7 | lgkm[11:8]=15 | vm[5:4]@[15:14]
constexpr unsigned vmcnt_enc(int n) {
    return (unsigned)((n & 15) | (7 << 4) | (15 << 8) | ((n >> 4) << 14));
}

// async global->LDS, 16B per lane: LDS dest = uniform base + lane*16, global src per-lane.
static __device__ __forceinline__ void lds_stage16(const f16* src, f16* dst) {
    typedef const __attribute__((address_space(1))) unsigned int* gup;
    typedef __attribute__((address_space(3))) unsigned int* lup;
    __builtin_amdgcn_global_load_lds((gup)(const void*)src, (lup)(void*)dst, 16, 0, 0);
}

// ---------------------------------------------------------------------------
// Tap-decomposed implicit-GEMM conv, f16 MFMA, 2-term activation split,
// fp32 accumulate.  R3: kernel is LATENCY-bound (12.9 TB/s L2 << 4.9/XCD
// ceiling, MfmaUtil 24%).  Changes: (1) A register pipeline deepened to D=8
// via compile-time 2-group phase unroll (flat-step slot = f % D); (2) B
// ds_read 2-ahead triple buffer (BAH); (3) B staged with global_load_lds --
// no stg regs, no ds_writes, group-end sync is counted vmcnt(2*STG) so the
// A global pipeline is NEVER drained; (4) setprio around MFMA cluster.
//   A-frag: lane&15=pixel, k=(lane>>4)*8+j ; B-frag: lane&15=oc, same k.
//   D-frag: col(oc)=lane&15, row(pixel)=(lane>>4)*4+reg  [HW-verified]
// ---------------------------------------------------------------------------
template <int KH, int KW, int KPT, int MODE, int NG, int NOC, int D, int STG, int BAH,
          int CBI, int KB0, int WPI, int PIXPI,
          int WSH, int HWOUT, int OC, int STRIDE, int POFF,
          int CBO, int OCH0, int WPO, int PIXPO>
static __device__ __forceinline__ void gemm_conv_body(
    int bx, int by, int b,
    const f16* Ah, const f16* Al, const f16* __restrict__ Wt,
    const float* __restrict__ bias, const float* __restrict__ zbuf,
    float* zout, f16* Oh, f16* Ol, f16* smem)
{
    constexpr int NSTEP = KH * KW * KPT;
    constexpr int WOUT  = 1 << WSH;
    constexpr int OCB   = OC / 16;
    constexpr int NGRP  = NSTEP / STG;
    constexpr int U     = (D > STG) ? (D / STG) : 1;   // phase-unroll factor
    constexpr int NB    = BAH + 1;                     // B ping-pong depth
    constexpr int PPW   = (STG * NOC) / 4;             // staged 1KB pieces per wave
    static_assert(NSTEP % STG == 0, "NSTEP % STG");
    static_assert(NSTEP % D == 0, "NSTEP % D");
    static_assert(U == 1 ? (STG % D == 0) : (D % STG == 0 && NGRP % U == 0), "phase");
    static_assert(BAH >= 1 && BAH < STG, "BAH range");
    static_assert(STG * NOC * 512 <= 8192, "group fits buffer");

    const int lane = threadIdx.x & 63;
    const int wave = threadIdx.x >> 6;
    const int pixbase = (bx * 4 + wave) * (NG * 16);
    const int ocbase  = by * (NOC * 16);

    const f16* ph[NG];
    const f16* pl[NG];
#pragma unroll
    for (int g = 0; g < NG; ++g) {
        int apix = pixbase + 16 * g + (lane & 15);
        int y = apix >> WSH, x = apix & (WOUT - 1);
        int p0 = (y * STRIDE + POFF) * WPI + (x * STRIDE + POFF);
        size_t o = ((size_t)(b * CBI + KB0) * PIXPI + p0) * 32 + (lane >> 4) * 8;
        ph[g] = Ah + o;
        pl[g] = Al + o;
    }

    int lk = 0, lkx = 0;
    auto advance = [&]() {
#pragma unroll
        for (int g = 0; g < NG; ++g) { ph[g] += (size_t)PIXPI * 32; pl[g] += (size_t)PIXPI * 32; }
        if (++lk == KPT) {
            lk = 0;
            int shift = 1;
            if (++lkx == KW) { lkx = 0; shift = WPI - (KW - 1); }
            const long ad = (long)shift * 32 - (long)KPT * PIXPI * 32;
#pragma unroll
            for (int g = 0; g < NG; ++g) { ph[g] += ad; pl[g] += ad; }
        }
    };

    // B piece (1KB = 512 f16 = [kgrp4][oc16][ch8]) for flat step s, oc-block j
    auto bpiece = [&](int s, int j) -> const f16* {
        int t = s / KPT, kb = s % KPT;
        return Wt + (((size_t)(t * OCB + by * NOC + j)) * KPT + kb) * 512;
    };

    auto stage_lds = [&](int g0, f16* dst) {
#pragma unroll
        for (int p = 0; p < PPW; ++p) {
            const int pc = wave * PPW + p;
            const int kk = pc / NOC, j = pc % NOC;
            lds_stage16(bpiece(g0 * STG + kk, j) + lane * 8, dst + pc * 512);
        }
    };

    half8 bh[D][NG], bl[D][NG];
    half8 bwreg[NB][NOC];
    f32x4 acc[NG][NOC] = {};
    f32x4 acc2[NG][NOC] = {};

    // prologue: stage group 0; fill A pipeline D-1 deep; certify B via counted vmcnt
    stage_lds(0, smem);
#pragma unroll
    for (int s = 0; s < D - 1; ++s) {
#pragma unroll
        for (int g = 0; g < NG; ++g) {
            bh[s][g] = *(const half8*)ph[g];
            bl[s][g] = *(const half8*)pl[g];
        }
        advance();
    }
    __builtin_amdgcn_s_waitcnt(vmcnt_enc((D - 1) * NG * 2));
    asm volatile("" ::: "memory");
    __builtin_amdgcn_s_barrier();
    __builtin_amdgcn_sched_barrier(0);

    auto group_body = [&](auto phc, int gi) __attribute__((always_inline)) {
        constexpr int PH = decltype(phc)::v;
        constexpr int PB = PH * STG;                 // flat-step phase base (mod D)
        const int par = (U == 2) ? PH : (gi & 1);
        f16* cur = smem + par * 8192;
        f16* nxt = smem + (par ^ 1) * 8192;
        if (gi + 1 < NGRP) stage_lds(gi + 1, nxt);   // async into other buffer
#pragma unroll
        for (int q = 0; q < BAH; ++q)
#pragma unroll
            for (int j = 0; j < NOC; ++j)
                bwreg[q % NB][j] = *(const half8*)(cur + (q * NOC + j) * 512 + lane * 8);
#pragma unroll
        for (int kk = 0; kk < STG; ++kk) {
            if (kk + BAH < STG) {
#pragma unroll
                for (int j = 0; j < NOC; ++j)
                    bwreg[(kk + BAH) % NB][j] = *(const half8*)(cur + ((kk + BAH) * NOC + j) * 512 + lane * 8);
            }
            const int ls = (PB + kk + D - 1) % D;    // compile-time after unroll
#pragma unroll
            for (int g = 0; g < NG; ++g) {
                bh[ls][g] = *(const half8*)ph[g];
                bl[ls][g] = *(const half8*)pl[g];
            }
            advance();
            const int dd = (PB + kk) % D;
            __builtin_amdgcn_s_setprio(1);
#pragma unroll
            for (int j = 0; j < NOC; ++j)
#pragma unroll
                for (int g = 0; g < NG; ++g) {
                    acc[g][j]  = __builtin_amdgcn_mfma_f32_16x16x32_f16(bh[dd][g], bwreg[kk % NB][j], acc[g][j], 0, 0, 0);
                    acc2[g][j] = __builtin_amdgcn_mfma_f32_16x16x32_f16(bl[dd][g], bwreg[kk % NB][j], acc2[g][j], 0, 0, 0);
                }
            __builtin_amdgcn_s_setprio(0);
        }
        if (gi + 1 < NGRP) {
            // certify own B-stage done (oldest); allow this group's STG*NG*2 A-loads in flight
            __builtin_amdgcn_s_waitcnt(vmcnt_enc(STG * NG * 2));
            asm volatile("" ::: "memory");
            __builtin_amdgcn_s_barrier();
            __builtin_amdgcn_sched_barrier(0);
        }
    };

#pragma unroll 1
    for (int gi0 = 0; gi0 < NGRP; gi0 += U) {
        group_body(ic<0>{}, gi0);
        if constexpr (U == 2) group_body(ic<1>{}, gi0 + 1);
    }

    constexpr int Cc = (MODE == 0) ? (OC >> 1) : OC;
#pragma unroll
    for (int g = 0; g < NG; ++g) {
#pragma unroll
        for (int j = 0; j < NOC; ++j) {
            const int oc = ocbase + j * 16 + (lane & 15);
            const float bv = bias[oc];
#pragma unroll
            for (int r = 0; r < 4; ++r) {
                const int pix = pixbase + 16 * g + ((lane >> 4) << 2) + r;
                const int y = pix >> WSH, x = pix & (WOUT - 1);
                const int pr = (y + 2) * WPI + (x + 2);
                const int pwr = (y + 2) * WPO + (x + 2);
                const size_t pz = (size_t)b * HWOUT + pix;
                float a = acc[g][j][r] + acc2[g][j][r] * (1.0f / 4096.0f) + bv;
                if (MODE == 0) {
                    float s = sigmoid_f(a);
                    if (oc < Cc) {
                        zout[pz * Cc + oc] = s;
                    } else {
                        int hch = oc - Cc;
                        size_t hidx = ((size_t)(b * CBI + (hch >> 5)) * PIXPI + pr) * 32 + (hch & 31);
                        float hv = (float)Ah[hidx] + (float)Al[hidx] * (1.0f / 4096.0f);
                        float rh = s * hv;
                        f16 hi, lo; splitf(rh, hi, lo);
                        int wch = Cc + oc;  // = 2C + (oc-C)
                        size_t widx = ((size_t)(b * CBO + (wch >> 5)) * PIXPO + pwr) * 32 + (wch & 31);
                        Oh[widx] = hi; Ol[widx] = lo;
                    }
                } else if (MODE == 1) {
                    size_t hidx = ((size_t)(b * CBI + (oc >> 5)) * PIXPI + pr) * 32 + (oc & 31);
                    float hv = (float)Ah[hidx] + (float)Al[hidx] * (1.0f / 4096.0f);
                    float zv = zbuf[pz * Cc + oc];
                    float hn = (1.f - zv) * hv + zv * tanhf(a);
                    f16 hi, lo; splitf(hn, hi, lo);
                    Oh[hidx] = hi; Ol[hidx] = lo;
                } else {
                    f16 hi, lo; splitf(a, hi, lo);
                    int wch = OCH0 + oc;
                    size_t widx = ((size_t)(b * CBO + (wch >> 5)) * PIXPO + pwr) * 32 + (wch & 31);
                    Oh[widx] = hi; Ol[widx] = lo;
                }
            }
        }
    }
}

// ---------------------------------------------------------------------------
// conv1 body: IC=1, k4 s2 p1, 128x128 -> 64x64, OC=64, fp32 direct; writes f16
// hi/lo into blocked cat1 xt region (ch [64,128), cblk 2..3, halo 2).
// ---------------------------------------------------------------------------
static __device__ __forceinline__ void conv1_body(
    int bx, int b,
    const float* __restrict__ in, const float* __restrict__ w,
    const float* __restrict__ bias, f16* Oh, f16* Ol)
{
    const int tid = threadIdx.x;
    const int px  = bx * 64 + (tid & 63);
    const int ocg = tid >> 6;
    const int y = px >> 6, x = px & 63;
    const float* src = in + (size_t)b * 196608;
    float v[16];
#pragma unroll
    for (int ky = 0; ky < 4; ++ky)
#pragma unroll
        for (int kx = 0; kx < 4; ++kx) {
            int iy = 2 * y - 1 + ky, ix = 2 * x - 1 + kx;
            v[ky * 4 + kx] = ((unsigned)iy < 128u && (unsigned)ix < 128u) ? src[iy * 128 + ix] : 0.f;
        }
    const int p = (y + 2) * 68 + (x + 2);
#pragma unroll
    for (int o = 0; o < 16; ++o) {
        int ch = 64 + ocg * 16 + o;
        float s = bias[ch - 64];
        const float* wr = w + (ch - 64) * 16;
#pragma unroll
        for (int t = 0; t < 16; ++t) s += wr[t] * v[t];
        f16 hi, lo; splitf(s, hi, lo);
        size_t idx = ((size_t)(b * 6 + (ch >> 5)) * 4624 + p) * 32 + (ch & 31);
        Oh[idx] = hi; Ol[idx] = lo;
    }
}

// ---------------------------------------------------------------------------
// Horizontally-fused pipeline phases.  GRU wavefront: stage1@t, stage2@t-1,
// stage3@t-2 are independent -> fuse each sub-phase across stages.
// Branch order = heaviest work-per-block first (LPT).
// ---------------------------------------------------------------------------

// L1: c2(t-1) [256] | c3(t-2) [128] | conv1(t) [512]  -> 896 blocks
__global__ __launch_bounds__(256) void fused_L1(
    const float* __restrict__ input, const float* __restrict__ c1w, const float* __restrict__ c1b,
    f16* cat1h, f16* cat1l,
    const f16* __restrict__ wt_c2, const float* __restrict__ c2b, f16* cat2h, f16* cat2l,
    const f16* __restrict__ wt_c3, const float* __restrict__ c3b, f16* cat3h, f16* cat3l,
    int t1, int a2, int a3)
{
    __shared__ f16 smem[2 * 8192];
    const int lin = blockIdx.x;
    if (lin < 256) {
        if (!a2) return;
        gemm_conv_body<4, 4, 2, 2, 1, 4, 8, 4, 1, 6, 0, 68, 4624, 5, 1024, 128, 2, 1, 12, 128, 36, 1296>(
            lin & 15, (lin >> 4) & 1, lin >> 5,
            cat1h, cat1l, wt_c2, c2b, nullptr, nullptr, cat2h, cat2l, smem);
    } else if (lin < 384) {
        if (!a3) return;
        const int l = lin - 256;
        gemm_conv_body<4, 4, 4, 2, 1, 2, 8, 8, 2, 12, 0, 36, 1296, 4, 256, 128, 2, 1, 12, 128, 20, 400>(
            l & 3, (l >> 2) & 3, l >> 4,
            cat2h, cat2l, wt_c3, c3b, nullptr, nullptr, cat3h, cat3l, smem);
    } else {
        if (t1 < 0) return;
        const int l = lin - 384;
        conv1_body(l & 63, l >> 6, input + (size_t)t1 * 16384, c1w, c1b, cat1h, cat1l);
    }
}

// L2: g2zr(t-1) [512] | g1zr(t) [1024] | g3zr(t-2) [256]  -> 1792 blocks
__global__ __launch_bounds__(256) void fused_L2(
    f16* cat1h, f16* cat1l, const f16* __restrict__ wt_g1zr, const float* __restrict__ g1zrb, float* z1,
    f16* cat2h, f16* cat2l, const f16* __restrict__ wt_g2zr, const float* __restrict__ g2zrb, float* z2,
    f16* cat3h, f16* cat3l, const f16* __restrict__ wt_g3zr, const float* __restrict__ g3zrb, float* z3,
    int a1, int a2, int a3)
{
    __shared__ f16 smem[2 * 8192];
    const int lin = blockIdx.x;
    if (lin < 512) {
        if (!a2) return;
        gemm_conv_body<5, 5, 8, 0, 1, 4, 8, 4, 1, 12, 0, 36, 1296, 5, 1024, 256, 1, 0, 12, 0, 36, 1296>(
            lin & 15, (lin >> 4) & 3, lin >> 6,
            cat2h, cat2l, wt_g2zr, g2zrb, nullptr, z2, cat2h, cat2l, smem);
    } else if (lin < 1536) {
        if (!a1) return;
        const int l = lin - 512;
        gemm_conv_body<5, 5, 4, 0, 1, 4, 4, 4, 2, 6, 0, 68, 4624, 6, 4096, 128, 1, 0, 6, 0, 68, 4624>(
            l & 63, (l >> 6) & 1, l >> 7,
            cat1h, cat1l, wt_g1zr, g1zrb, nullptr, z1, cat1h, cat1l, smem);
    } else {
        if (!a3) return;
        const int l = lin - 1536;
        gemm_conv_body<5, 5, 8, 0, 1, 2, 8, 8, 2, 12, 0, 20, 400, 4, 256, 256, 1, 0, 12, 0, 20, 400>(
            l & 3, (l >> 2) & 7, l >> 5,
            cat3h, cat3l, wt_g3zr, g3zrb, nullptr, z3, cat3h, cat3l, smem);
    }
}

// L3: g2h(t-1) [256] | g1h(t) [512] | g3h(t-2) [128]  -> 896 blocks
__global__ __launch_bounds__(256) void fused_L3(
    f16* cat1h, f16* cat1l, const f16* __restrict__ wt_g1h, const float* __restrict__ g1hb, const float* z1,
    f16* cat2h, f16* cat2l, const f16* __restrict__ wt_g2h, const float* __restrict__ g2hb, const float* z2,
    f16* cat3h, f16* cat3l, const f16* __restrict__ wt_g3h, const float* __restrict__ g3hb, const float* z3,
    int a1, int a2, int a3)
{
    __shared__ f16 smem[2 * 8192];
    const int lin = blockIdx.x;
    if (lin < 256) {
        if (!a2) return;
        gemm_conv_body<5, 5, 8, 1, 1, 4, 8, 4, 1, 12, 4, 36, 1296, 5, 1024, 128, 1, 0, 12, 0, 36, 1296>(
            lin & 15, (lin >> 4) & 1, lin >> 5,
            cat2h, cat2l, wt_g2h, g2hb, z2, nullptr, cat2h, cat2l, smem);
    } else if (lin < 768) {
        if (!a1) return;
        const int l = lin - 256;
        gemm_conv_body<5, 5, 4, 1, 1, 4, 4, 4, 2, 6, 2, 68, 4624, 6, 4096, 64, 1, 0, 6, 0, 68, 4624>(
            l & 63, 0, l >> 6,
            cat1h, cat1l, wt_g1h, g1hb, z1, nullptr, cat1h, cat1l, smem);
    } else {
        if (!a3) return;
        const int l = lin - 768;
        gemm_conv_body<5, 5, 8, 1, 1, 2, 8, 8, 2, 12, 4, 20, 400, 4, 256, 128, 1, 0, 12, 0, 20, 400>(
            l & 3, (l >> 2) & 3, l >> 4,
            cat3h, cat3l, wt_g3h, g3hb, z3, nullptr, cat3h, cat3l, smem);
    }
}

// w[oc][ic][kh][kw] fp32 -> blocked f16 [tap][ocblk][kblk][kgrp4][oc16][ch8].
// perm=1: swap input-channel halves (zr convs: ref concat [x,h] -> cat [h,xt]).
__global__ __launch_bounds__(256) void prep_w(
    const float* __restrict__ w, f16* __restrict__ wt,
    int OC, int IC, int KK, int perm)
{
    int i = blockIdx.x * 256 + threadIdx.x;
    int total = OC * IC * KK;
    if (i >= total) return;
    int oc = i / (IC * KK);
    int r  = i - oc * (IC * KK);
    int ic = r / KK;
    int tap = r - ic * KK;
    int icn = perm ? ((ic < IC / 2) ? ic + IC / 2 : ic - IC / 2) : ic;
    int OCB = OC >> 4, KPT = IC >> 5;
    int ob = oc >> 4, ol = oc & 15;
    int kb = icn >> 5, kg = (icn >> 3) & 3, ch = icn & 7;
    size_t o = (((size_t)tap * OCB + ob) * KPT + kb) * 512 + kg * 128 + ol * 8 + ch;
    wt[o] = (f16)w[i];
}

// blocked cat hi/lo h-region -> fp32 NCHW
__global__ __launch_bounds__(256) void cat_to_nchw(
    const f16* __restrict__ hi, const f16* __restrict__ lo,
    float* __restrict__ dst, int C, int HW, int wsh, int WP, int PIXP, int CB)
{
    int i = blockIdx.x * 256 + threadIdx.x;
    int b = i / (C * HW);
    int r = i - b * (C * HW);
    int c = r / HW;
    int p = r - c * HW;
    int y = p >> wsh, x = p & ((1 << wsh) - 1);
    size_t s = ((size_t)(b * CB + (c >> 5)) * PIXP + (size_t)(y + 2) * WP + (x + 2)) * 32 + (c & 31);
    dst[i] = (float)hi[s] + (float)lo[s] * (1.0f / 4096.0f);
}

// ---------------------------------------------------------------------------
extern "C" void kernel_launch(void* const* d_in, const int* in_sizes, int n_in,
                              void* d_out, int out_size, void* d_ws, size_t ws_size,
                              hipStream_t stream)
{
    (void)in_sizes; (void)n_in; (void)out_size; (void)ws_size;

    const float* input  = (const float*)d_in[0];
    const float* c1_w   = (const float*)d_in[1];
    const float* c1_b   = (const float*)d_in[2];
    const float* g1zr_w = (const float*)d_in[3];
    const float* g1zr_b = (const float*)d_in[4];
    const float* g1h_w  = (const float*)d_in[5];
    const float* g1h_b  = (const float*)d_in[6];
    const float* c2_w   = (const float*)d_in[7];
    const float* c2_b   = (const float*)d_in[8];
    const float* g2zr_w = (const float*)d_in[9];
    const float* g2zr_b = (const float*)d_in[10];
    const float* g2h_w  = (const float*)d_in[11];
    const float* g2h_b  = (const float*)d_in[12];
    const float* c3_w   = (const float*)d_in[13];
    const float* c3_b   = (const float*)d_in[14];
    const float* g3zr_w = (const float*)d_in[15];
    const float* g3zr_b = (const float*)d_in[16];
    const float* g3h_w  = (const float*)d_in[17];
    const float* g3h_b  = (const float*)d_in[18];

    float* out1 = (float*)d_out;                 // [8,64,64,64]  NCHW
    float* out2 = (float*)d_out + 2097152;       // [8,128,32,32]
    float* out3 = (float*)d_out + 3145728;       // [8,128,16,16]

    char* ws = (char*)d_ws;
    size_t off = 0;
    auto takeB = [&](size_t bytes) { char* p = ws + off; off += (bytes + 255) & ~(size_t)255; return p; };

    const size_t WSLACK = 400000;
    f16* wt_g1zr = (f16*)takeB((size_t)25 * 128 * 128 * 2 + WSLACK);
    f16* wt_g1h  = (f16*)takeB((size_t)25 * 64 * 128 * 2 + WSLACK);
    f16* wt_c2   = (f16*)takeB((size_t)16 * 128 * 64 * 2 + WSLACK);
    f16* wt_g2zr = (f16*)takeB((size_t)25 * 256 * 256 * 2 + WSLACK);
    f16* wt_g2h  = (f16*)takeB((size_t)25 * 128 * 256 * 2 + WSLACK);
    f16* wt_c3   = (f16*)takeB((size_t)16 * 128 * 128 * 2 + WSLACK);
    f16* wt_g3zr = (f16*)takeB((size_t)25 * 256 * 256 * 2 + WSLACK);
    f16* wt_g3h  = (f16*)takeB((size_t)25 * 128 * 256 * 2 + WSLACK);

    // blocked padded cat buffers: [b][cblk][pixP][32], hi/lo planes
    const size_t cat1_n = (size_t)8 * 6 * 4624 * 32;   // 68x68, 192ch
    const size_t cat2_n = (size_t)8 * 12 * 1296 * 32;  // 36x36, 384ch
    const size_t cat3_n = (size_t)8 * 12 * 400 * 32;   // 20x20, 384ch
    const size_t ASLACK = 1 << 20;
    f16* cat1h = (f16*)takeB(cat1_n * 2 + ASLACK);
    f16* cat1l = (f16*)takeB(cat1_n * 2 + ASLACK);
    f16* cat2h = (f16*)takeB(cat2_n * 2 + ASLACK);
    f16* cat2l = (f16*)takeB(cat2_n * 2 + ASLACK);
    f16* cat3h = (f16*)takeB(cat3_n * 2 + ASLACK);
    f16* cat3l = (f16*)takeB(cat3_n * 2 + ASLACK);
    float* z1 = (float*)takeB((size_t)8 * 4096 * 64 * 4);
    float* z2 = (float*)takeB((size_t)8 * 1024 * 128 * 4);
    float* z3 = (float*)takeB((size_t)8 * 256 * 128 * 4);

    hipMemsetAsync(cat1h, 0, cat1_n * 2, stream);
    hipMemsetAsync(cat1l, 0, cat1_n * 2, stream);
    hipMemsetAsync(cat2h, 0, cat2_n * 2, stream);
    hipMemsetAsync(cat2l, 0, cat2_n * 2, stream);
    hipMemsetAsync(cat3h, 0, cat3_n * 2, stream);
    hipMemsetAsync(cat3l, 0, cat3_n * 2, stream);

    auto prep = [&](const float* w, f16* wt, int OC, int IC, int KK, int perm) {
        int total = OC * IC * KK;
        prep_w<<<(total + 255) / 256, 256, 0, stream>>>(w, wt, OC, IC, KK, perm);
    };
    prep(g1zr_w, wt_g1zr, 128, 128, 25, 1);
    prep(g1h_w,  wt_g1h,  64, 128, 25, 0);
    prep(c2_w,   wt_c2,   128, 64, 16, 0);
    prep(g2zr_w, wt_g2zr, 256, 256, 25, 1);
    prep(g2h_w,  wt_g2h,  128, 256, 25, 0);
    prep(c3_w,   wt_c3,   128, 128, 16, 0);
    prep(g3zr_w, wt_g3zr, 256, 256, 25, 1);
    prep(g3h_w,  wt_g3h,  128, 256, 25, 0);

    // Software-pipelined wavefront: iteration i runs stage1@t=i, stage2@t=i-1,
    // stage3@t=i-2.  12 steps -> 14 iterations (2 fill, 2 drain).
    for (int i = 0; i < 14; ++i) {
        const int t1 = (i < 12) ? i : -1;
        const int a1 = (i < 12) ? 1 : 0;
        const int a2 = (i >= 1 && i <= 12) ? 1 : 0;
        const int a3 = (i >= 2) ? 1 : 0;

        fused_L1<<<896, 256, 0, stream>>>(
            input, c1_w, c1_b, cat1h, cat1l,
            wt_c2, c2_b, cat2h, cat2l,
            wt_c3, c3_b, cat3h, cat3l,
            t1, a2, a3);
        fused_L2<<<1792, 256, 0, stream>>>(
            cat1h, cat1l, wt_g1zr, g1zr_b, z1,
            cat2h, cat2l, wt_g2zr, g2zr_b, z2,
            cat3h, cat3l, wt_g3zr, g3zr_b, z3,
            a1, a2, a3);
        fused_L3<<<896, 256, 0, stream>>>(
            cat1h, cat1l, wt_g1h, g1h_b, z1,
            cat2h, cat2l, wt_g2h, g2h_b, z2,
            cat3h, cat3l, wt_g3h, g3h_b, z3,
            a1, a2, a3);
    }

    cat_to_nchw<<<8192, 256, 0, stream>>>(cat1h, cat1l, out1, 64, 4096, 6, 68, 4624, 6);
    cat_to_nchw<<<4096, 256, 0, stream>>>(cat2h, cat2l, out2, 128, 1024, 5, 36, 1296, 12);
    cat_to_nchw<<<1024, 256, 0, stream>>>(cat3h, cat3l, out3, 128, 256, 4, 20, 400, 12);
}

// Round 4
// 3785.905 us; speedup vs baseline: 1.4150x; 1.0404x over previous
//
#include <hip/hip_runtime.h>
#include <math.h>

typedef _Float16 f16;
typedef __attribute__((ext_vector_type(8))) _Float16 half8;
typedef __attribute__((ext_vector_type(4))) float f32x4;

template <int N> struct ic { static constexpr int v = N; };

static __device__ __forceinline__ float sigmoid_f(float x) { return 1.0f / (1.0f + expf(-x)); }

// exact split: x == (float)hi + (float)lo / 4096 (lo pre-scaled to dodge denormals)
static __device__ __forceinline__ void splitf(float x, f16& hi, f16& lo) {
    hi = (f16)x;
    float r = x - (float)hi;
    lo = (f16)(r * 4096.0f);
}

// vmcnt-only s_waitcnt immediate (gfx9 encoding): vm[3:0] | exp[6:4]=7 | lgkm[11:8]=15 | vm[5:4]@[15:14]
constexpr unsigned vmcnt_enc(int n) {
    return (unsigned)((n & 15) | (7 << 4) | (15 << 8) | ((n >> 4) << 14));
}

// async global->LDS, 16B per lane: LDS dest = uniform base + lane*16, global src per-lane.
static __device__ __forceinline__ void lds_stage16(const f16* src, f16* dst) {
    typedef const __attribute__((address_space(1))) unsigned int* gup;
    typedef __attribute__((address_space(3))) unsigned int* lup;
    __builtin_amdgcn_global_load_lds((gup)(const void*)src, (lup)(void*)dst, 16, 0, 0);
}

// ---------------------------------------------------------------------------
// Tap-decomposed implicit-GEMM conv, f16 MFMA, 2-term activation split,
// fp32 accumulate.  R4: R3's VGPR_Count=80 proved the compiler SANK the
// D-deep A-loads (pipeline collapsed).  Fixes: (1) per-step sched_barrier(0)
// between loads and MFMA cluster -- loads may hoist but cannot sink, forcing
// the D-deep A / BAH-deep B pipelines into registers; (2) BAH=2 (NOC=4) /
// BAH=3 (NOC=2) so B ds_reads lead their use by ~2-3 steps (~LDS latency);
// (3) LPT block ordering in the fused launchers (longest branch first).
//   A-frag: lane&15=pixel, k=(lane>>4)*8+j ; B-frag: lane&15=oc, same k.
//   D-frag: col(oc)=lane&15, row(pixel)=(lane>>4)*4+reg  [HW-verified]
// ---------------------------------------------------------------------------
template <int KH, int KW, int KPT, int MODE, int NG, int NOC, int D, int STG, int BAH,
          int CBI, int KB0, int WPI, int PIXPI,
          int WSH, int HWOUT, int OC, int STRIDE, int POFF,
          int CBO, int OCH0, int WPO, int PIXPO>
static __device__ __forceinline__ void gemm_conv_body(
    int bx, int by, int b,
    const f16* Ah, const f16* Al, const f16* __restrict__ Wt,
    const float* __restrict__ bias, const float* __restrict__ zbuf,
    float* zout, f16* Oh, f16* Ol, f16* smem)
{
    constexpr int NSTEP = KH * KW * KPT;
    constexpr int WOUT  = 1 << WSH;
    constexpr int OCB   = OC / 16;
    constexpr int NGRP  = NSTEP / STG;
    constexpr int U     = (D > STG) ? (D / STG) : 1;   // phase-unroll factor
    constexpr int NB    = BAH + 1;                     // B ring depth
    constexpr int PPW   = (STG * NOC) / 4;             // staged 1KB pieces per wave
    static_assert(NSTEP % STG == 0, "NSTEP % STG");
    static_assert(NSTEP % D == 0, "NSTEP % D");
    static_assert(U == 1 ? (STG % D == 0) : (D % STG == 0 && NGRP % U == 0), "phase");
    static_assert(BAH >= 1 && BAH < STG, "BAH range");
    static_assert(STG * NOC * 512 <= 8192, "group fits buffer");

    const int lane = threadIdx.x & 63;
    const int wave = threadIdx.x >> 6;
    const int pixbase = (bx * 4 + wave) * (NG * 16);
    const int ocbase  = by * (NOC * 16);

    const f16* ph[NG];
    const f16* pl[NG];
#pragma unroll
    for (int g = 0; g < NG; ++g) {
        int apix = pixbase + 16 * g + (lane & 15);
        int y = apix >> WSH, x = apix & (WOUT - 1);
        int p0 = (y * STRIDE + POFF) * WPI + (x * STRIDE + POFF);
        size_t o = ((size_t)(b * CBI + KB0) * PIXPI + p0) * 32 + (lane >> 4) * 8;
        ph[g] = Ah + o;
        pl[g] = Al + o;
    }

    int lk = 0, lkx = 0;
    auto advance = [&]() {
#pragma unroll
        for (int g = 0; g < NG; ++g) { ph[g] += (size_t)PIXPI * 32; pl[g] += (size_t)PIXPI * 32; }
        if (++lk == KPT) {
            lk = 0;
            int shift = 1;
            if (++lkx == KW) { lkx = 0; shift = WPI - (KW - 1); }
            const long ad = (long)shift * 32 - (long)KPT * PIXPI * 32;
#pragma unroll
            for (int g = 0; g < NG; ++g) { ph[g] += ad; pl[g] += ad; }
        }
    };

    // B piece (1KB = 512 f16 = [kgrp4][oc16][ch8]) for flat step s, oc-block j
    auto bpiece = [&](int s, int j) -> const f16* {
        int t = s / KPT, kb = s % KPT;
        return Wt + (((size_t)(t * OCB + by * NOC + j)) * KPT + kb) * 512;
    };

    auto stage_lds = [&](int g0, f16* dst) {
#pragma unroll
        for (int p = 0; p < PPW; ++p) {
            const int pc = wave * PPW + p;
            const int kk = pc / NOC, j = pc % NOC;
            lds_stage16(bpiece(g0 * STG + kk, j) + lane * 8, dst + pc * 512);
        }
    };

    half8 bh[D][NG], bl[D][NG];
    half8 bwreg[NB][NOC];
    f32x4 acc[NG][NOC] = {};
    f32x4 acc2[NG][NOC] = {};

    // prologue: stage group 0; fill A pipeline D-1 deep; certify B via counted vmcnt
    stage_lds(0, smem);
#pragma unroll
    for (int s = 0; s < D - 1; ++s) {
#pragma unroll
        for (int g = 0; g < NG; ++g) {
            bh[s][g] = *(const half8*)ph[g];
            bl[s][g] = *(const half8*)pl[g];
        }
        advance();
    }
    __builtin_amdgcn_s_waitcnt(vmcnt_enc((D - 1) * NG * 2));
    asm volatile("" ::: "memory");
    __builtin_amdgcn_s_barrier();
    __builtin_amdgcn_sched_barrier(0);

    auto group_body = [&](auto phc, int gi) __attribute__((always_inline)) {
        constexpr int PH = decltype(phc)::v;
        constexpr int PB = PH * STG;                 // flat-step phase base (mod D)
        const int par = (U == 2) ? PH : (gi & 1);
        f16* cur = smem + par * 8192;
        f16* nxt = smem + (par ^ 1) * 8192;
        if (gi + 1 < NGRP) stage_lds(gi + 1, nxt);   // async into other buffer
#pragma unroll
        for (int q = 0; q < BAH; ++q)
#pragma unroll
            for (int j = 0; j < NOC; ++j)
                bwreg[q % NB][j] = *(const half8*)(cur + (q * NOC + j) * 512 + lane * 8);
#pragma unroll
        for (int kk = 0; kk < STG; ++kk) {
            if (kk + BAH < STG) {
#pragma unroll
                for (int j = 0; j < NOC; ++j)
                    bwreg[(kk + BAH) % NB][j] = *(const half8*)(cur + ((kk + BAH) * NOC + j) * 512 + lane * 8);
            }
            const int ls = (PB + kk + D - 1) % D;    // compile-time after unroll
#pragma unroll
            for (int g = 0; g < NG; ++g) {
                bh[ls][g] = *(const half8*)ph[g];
                bl[ls][g] = *(const half8*)pl[g];
            }
            advance();
            // Pin: loads above may hoist (deeper pipeline) but cannot sink
            // below this point -- forces D-deep A / BAH-deep B live ranges.
            __builtin_amdgcn_sched_barrier(0);
            const int dd = (PB + kk) % D;
            __builtin_amdgcn_s_setprio(1);
#pragma unroll
            for (int j = 0; j < NOC; ++j)
#pragma unroll
                for (int g = 0; g < NG; ++g) {
                    acc[g][j]  = __builtin_amdgcn_mfma_f32_16x16x32_f16(bh[dd][g], bwreg[kk % NB][j], acc[g][j], 0, 0, 0);
                    acc2[g][j] = __builtin_amdgcn_mfma_f32_16x16x32_f16(bl[dd][g], bwreg[kk % NB][j], acc2[g][j], 0, 0, 0);
                }
            __builtin_amdgcn_s_setprio(0);
        }
        if (gi + 1 < NGRP) {
            // certify own B-stage done (oldest); allow this group's STG*NG*2 A-loads in flight
            __builtin_amdgcn_s_waitcnt(vmcnt_enc(STG * NG * 2));
            asm volatile("" ::: "memory");
            __builtin_amdgcn_s_barrier();
            __builtin_amdgcn_sched_barrier(0);
        }
    };

#pragma unroll 1
    for (int gi0 = 0; gi0 < NGRP; gi0 += U) {
        group_body(ic<0>{}, gi0);
        if constexpr (U == 2) group_body(ic<1>{}, gi0 + 1);
    }

    constexpr int Cc = (MODE == 0) ? (OC >> 1) : OC;
#pragma unroll
    for (int g = 0; g < NG; ++g) {
#pragma unroll
        for (int j = 0; j < NOC; ++j) {
            const int oc = ocbase + j * 16 + (lane & 15);
            const float bv = bias[oc];
#pragma unroll
            for (int r = 0; r < 4; ++r) {
                const int pix = pixbase + 16 * g + ((lane >> 4) << 2) + r;
                const int y = pix >> WSH, x = pix & (WOUT - 1);
                const int pr = (y + 2) * WPI + (x + 2);
                const int pwr = (y + 2) * WPO + (x + 2);
                const size_t pz = (size_t)b * HWOUT + pix;
                float a = acc[g][j][r] + acc2[g][j][r] * (1.0f / 4096.0f) + bv;
                if (MODE == 0) {
                    float s = sigmoid_f(a);
                    if (oc < Cc) {
                        zout[pz * Cc + oc] = s;
                    } else {
                        int hch = oc - Cc;
                        size_t hidx = ((size_t)(b * CBI + (hch >> 5)) * PIXPI + pr) * 32 + (hch & 31);
                        float hv = (float)Ah[hidx] + (float)Al[hidx] * (1.0f / 4096.0f);
                        float rh = s * hv;
                        f16 hi, lo; splitf(rh, hi, lo);
                        int wch = Cc + oc;  // = 2C + (oc-C)
                        size_t widx = ((size_t)(b * CBO + (wch >> 5)) * PIXPO + pwr) * 32 + (wch & 31);
                        Oh[widx] = hi; Ol[widx] = lo;
                    }
                } else if (MODE == 1) {
                    size_t hidx = ((size_t)(b * CBI + (oc >> 5)) * PIXPI + pr) * 32 + (oc & 31);
                    float hv = (float)Ah[hidx] + (float)Al[hidx] * (1.0f / 4096.0f);
                    float zv = zbuf[pz * Cc + oc];
                    float hn = (1.f - zv) * hv + zv * tanhf(a);
                    f16 hi, lo; splitf(hn, hi, lo);
                    Oh[hidx] = hi; Ol[hidx] = lo;
                } else {
                    f16 hi, lo; splitf(a, hi, lo);
                    int wch = OCH0 + oc;
                    size_t widx = ((size_t)(b * CBO + (wch >> 5)) * PIXPO + pwr) * 32 + (wch & 31);
                    Oh[widx] = hi; Ol[widx] = lo;
                }
            }
        }
    }
}

// ---------------------------------------------------------------------------
// conv1 body: IC=1, k4 s2 p1, 128x128 -> 64x64, OC=64, fp32 direct; writes f16
// hi/lo into blocked cat1 xt region (ch [64,128), cblk 2..3, halo 2).
// ---------------------------------------------------------------------------
static __device__ __forceinline__ void conv1_body(
    int bx, int b,
    const float* __restrict__ in, const float* __restrict__ w,
    const float* __restrict__ bias, f16* Oh, f16* Ol)
{
    const int tid = threadIdx.x;
    const int px  = bx * 64 + (tid & 63);
    const int ocg = tid >> 6;
    const int y = px >> 6, x = px & 63;
    const float* src = in + (size_t)b * 196608;
    float v[16];
#pragma unroll
    for (int ky = 0; ky < 4; ++ky)
#pragma unroll
        for (int kx = 0; kx < 4; ++kx) {
            int iy = 2 * y - 1 + ky, ix = 2 * x - 1 + kx;
            v[ky * 4 + kx] = ((unsigned)iy < 128u && (unsigned)ix < 128u) ? src[iy * 128 + ix] : 0.f;
        }
    const int p = (y + 2) * 68 + (x + 2);
#pragma unroll
    for (int o = 0; o < 16; ++o) {
        int ch = 64 + ocg * 16 + o;
        float s = bias[ch - 64];
        const float* wr = w + (ch - 64) * 16;
#pragma unroll
        for (int t = 0; t < 16; ++t) s += wr[t] * v[t];
        f16 hi, lo; splitf(s, hi, lo);
        size_t idx = ((size_t)(b * 6 + (ch >> 5)) * 4624 + p) * 32 + (ch & 31);
        Oh[idx] = hi; Ol[idx] = lo;
    }
}

// ---------------------------------------------------------------------------
// Horizontally-fused pipeline phases.  GRU wavefront: stage1@t, stage2@t-1,
// stage3@t-2 are independent -> fuse each sub-phase across stages.
// LPT ordering: longest-running branch gets the LOWEST block IDs.
// ---------------------------------------------------------------------------

// L1: c3(t-2) [0,128) | c2(t-1) [128,384) | conv1(t) [384,896)
__global__ __launch_bounds__(256) void fused_L1(
    const float* __restrict__ input, const float* __restrict__ c1w, const float* __restrict__ c1b,
    f16* cat1h, f16* cat1l,
    const f16* __restrict__ wt_c2, const float* __restrict__ c2b, f16* cat2h, f16* cat2l,
    const f16* __restrict__ wt_c3, const float* __restrict__ c3b, f16* cat3h, f16* cat3l,
    int t1, int a2, int a3)
{
    __shared__ f16 smem[2 * 8192];
    const int lin = blockIdx.x;
    if (lin < 128) {
        if (!a3) return;
        gemm_conv_body<4, 4, 4, 2, 1, 2, 8, 8, 3, 12, 0, 36, 1296, 4, 256, 128, 2, 1, 12, 128, 20, 400>(
            lin & 3, (lin >> 2) & 3, lin >> 4,
            cat2h, cat2l, wt_c3, c3b, nullptr, nullptr, cat3h, cat3l, smem);
    } else if (lin < 384) {
        if (!a2) return;
        const int l = lin - 128;
        gemm_conv_body<4, 4, 2, 2, 1, 4, 8, 4, 2, 6, 0, 68, 4624, 5, 1024, 128, 2, 1, 12, 128, 36, 1296>(
            l & 15, (l >> 4) & 1, l >> 5,
            cat1h, cat1l, wt_c2, c2b, nullptr, nullptr, cat2h, cat2l, smem);
    } else {
        if (t1 < 0) return;
        const int l = lin - 384;
        conv1_body(l & 63, l >> 6, input + (size_t)t1 * 16384, c1w, c1b, cat1h, cat1l);
    }
}

// L2: g2zr(t-1) [0,512) | g3zr(t-2) [512,768) | g1zr(t) [768,1792)
__global__ __launch_bounds__(256) void fused_L2(
    f16* cat1h, f16* cat1l, const f16* __restrict__ wt_g1zr, const float* __restrict__ g1zrb, float* z1,
    f16* cat2h, f16* cat2l, const f16* __restrict__ wt_g2zr, const float* __restrict__ g2zrb, float* z2,
    f16* cat3h, f16* cat3l, const f16* __restrict__ wt_g3zr, const float* __restrict__ g3zrb, float* z3,
    int a1, int a2, int a3)
{
    __shared__ f16 smem[2 * 8192];
    const int lin = blockIdx.x;
    if (lin < 512) {
        if (!a2) return;
        gemm_conv_body<5, 5, 8, 0, 1, 4, 8, 4, 2, 12, 0, 36, 1296, 5, 1024, 256, 1, 0, 12, 0, 36, 1296>(
            lin & 15, (lin >> 4) & 3, lin >> 6,
            cat2h, cat2l, wt_g2zr, g2zrb, nullptr, z2, cat2h, cat2l, smem);
    } else if (lin < 768) {
        if (!a3) return;
        const int l = lin - 512;
        gemm_conv_body<5, 5, 8, 0, 1, 2, 8, 8, 3, 12, 0, 20, 400, 4, 256, 256, 1, 0, 12, 0, 20, 400>(
            l & 3, (l >> 2) & 7, l >> 5,
            cat3h, cat3l, wt_g3zr, g3zrb, nullptr, z3, cat3h, cat3l, smem);
    } else {
        if (!a1) return;
        const int l = lin - 768;
        gemm_conv_body<5, 5, 4, 0, 1, 4, 4, 4, 2, 6, 0, 68, 4624, 6, 4096, 128, 1, 0, 6, 0, 68, 4624>(
            l & 63, (l >> 6) & 1, l >> 7,
            cat1h, cat1l, wt_g1zr, g1zrb, nullptr, z1, cat1h, cat1l, smem);
    }
}

// L3: g2h(t-1) [0,256) | g3h(t-2) [256,384) | g1h(t) [384,896)
__global__ __launch_bounds__(256) void fused_L3(
    f16* cat1h, f16* cat1l, const f16* __restrict__ wt_g1h, const float* __restrict__ g1hb, const float* z1,
    f16* cat2h, f16* cat2l, const f16* __restrict__ wt_g2h, const float* __restrict__ g2hb, const float* z2,
    f16* cat3h, f16* cat3l, const f16* __restrict__ wt_g3h, const float* __restrict__ g3hb, const float* z3,
    int a1, int a2, int a3)
{
    __shared__ f16 smem[2 * 8192];
    const int lin = blockIdx.x;
    if (lin < 256) {
        if (!a2) return;
        gemm_conv_body<5, 5, 8, 1, 1, 4, 8, 4, 2, 12, 4, 36, 1296, 5, 1024, 128, 1, 0, 12, 0, 36, 1296>(
            lin & 15, (lin >> 4) & 1, lin >> 5,
            cat2h, cat2l, wt_g2h, g2hb, z2, nullptr, cat2h, cat2l, smem);
    } else if (lin < 384) {
        if (!a3) return;
        const int l = lin - 256;
        gemm_conv_body<5, 5, 8, 1, 1, 2, 8, 8, 3, 12, 4, 20, 400, 4, 256, 128, 1, 0, 12, 0, 20, 400>(
            l & 3, (l >> 2) & 3, l >> 4,
            cat3h, cat3l, wt_g3h, g3hb, z3, nullptr, cat3h, cat3l, smem);
    } else {
        if (!a1) return;
        const int l = lin - 384;
        gemm_conv_body<5, 5, 4, 1, 1, 4, 4, 4, 2, 6, 2, 68, 4624, 6, 4096, 64, 1, 0, 6, 0, 68, 4624>(
            l & 63, 0, l >> 6,
            cat1h, cat1l, wt_g1h, g1hb, z1, nullptr, cat1h, cat1l, smem);
    }
}

// w[oc][ic][kh][kw] fp32 -> blocked f16 [tap][ocblk][kblk][kgrp4][oc16][ch8].
// perm=1: swap input-channel halves (zr convs: ref concat [x,h] -> cat [h,xt]).
__global__ __launch_bounds__(256) void prep_w(
    const float* __restrict__ w, f16* __restrict__ wt,
    int OC, int IC, int KK, int perm)
{
    int i = blockIdx.x * 256 + threadIdx.x;
    int total = OC * IC * KK;
    if (i >= total) return;
    int oc = i / (IC * KK);
    int r  = i - oc * (IC * KK);
    int ic = r / KK;
    int tap = r - ic * KK;
    int icn = perm ? ((ic < IC / 2) ? ic + IC / 2 : ic - IC / 2) : ic;
    int OCB = OC >> 4, KPT = IC >> 5;
    int ob = oc >> 4, ol = oc & 15;
    int kb = icn >> 5, kg = (icn >> 3) & 3, ch = icn & 7;
    size_t o = (((size_t)tap * OCB + ob) * KPT + kb) * 512 + kg * 128 + ol * 8 + ch;
    wt[o] = (f16)w[i];
}

// blocked cat hi/lo h-region -> fp32 NCHW
__global__ __launch_bounds__(256) void cat_to_nchw(
    const f16* __restrict__ hi, const f16* __restrict__ lo,
    float* __restrict__ dst, int C, int HW, int wsh, int WP, int PIXP, int CB)
{
    int i = blockIdx.x * 256 + threadIdx.x;
    int b = i / (C * HW);
    int r = i - b * (C * HW);
    int c = r / HW;
    int p = r - c * HW;
    int y = p >> wsh, x = p & ((1 << wsh) - 1);
    size_t s = ((size_t)(b * CB + (c >> 5)) * PIXP + (size_t)(y + 2) * WP + (x + 2)) * 32 + (c & 31);
    dst[i] = (float)hi[s] + (float)lo[s] * (1.0f / 4096.0f);
}

// ---------------------------------------------------------------------------
extern "C" void kernel_launch(void* const* d_in, const int* in_sizes, int n_in,
                              void* d_out, int out_size, void* d_ws, size_t ws_size,
                              hipStream_t stream)
{
    (void)in_sizes; (void)n_in; (void)out_size; (void)ws_size;

    const float* input  = (const float*)d_in[0];
    const float* c1_w   = (const float*)d_in[1];
    const float* c1_b   = (const float*)d_in[2];
    const float* g1zr_w = (const float*)d_in[3];
    const float* g1zr_b = (const float*)d_in[4];
    const float* g1h_w  = (const float*)d_in[5];
    const float* g1h_b  = (const float*)d_in[6];
    const float* c2_w   = (const float*)d_in[7];
    const float* c2_b   = (const float*)d_in[8];
    const float* g2zr_w = (const float*)d_in[9];
    const float* g2zr_b = (const float*)d_in[10];
    const float* g2h_w  = (const float*)d_in[11];
    const float* g2h_b  = (const float*)d_in[12];
    const float* c3_w   = (const float*)d_in[13];
    const float* c3_b   = (const float*)d_in[14];
    const float* g3zr_w = (const float*)d_in[15];
    const float* g3zr_b = (const float*)d_in[16];
    const float* g3h_w  = (const float*)d_in[17];
    const float* g3h_b  = (const float*)d_in[18];

    float* out1 = (float*)d_out;                 // [8,64,64,64]  NCHW
    float* out2 = (float*)d_out + 2097152;       // [8,128,32,32]
    float* out3 = (float*)d_out + 3145728;       // [8,128,16,16]

    char* ws = (char*)d_ws;
    size_t off = 0;
    auto takeB = [&](size_t bytes) { char* p = ws + off; off += (bytes + 255) & ~(size_t)255; return p; };

    const size_t WSLACK = 400000;
    f16* wt_g1zr = (f16*)takeB((size_t)25 * 128 * 128 * 2 + WSLACK);
    f16* wt_g1h  = (f16*)takeB((size_t)25 * 64 * 128 * 2 + WSLACK);
    f16* wt_c2   = (f16*)takeB((size_t)16 * 128 * 64 * 2 + WSLACK);
    f16* wt_g2zr = (f16*)takeB((size_t)25 * 256 * 256 * 2 + WSLACK);
    f16* wt_g2h  = (f16*)takeB((size_t)25 * 128 * 256 * 2 + WSLACK);
    f16* wt_c3   = (f16*)takeB((size_t)16 * 128 * 128 * 2 + WSLACK);
    f16* wt_g3zr = (f16*)takeB((size_t)25 * 256 * 256 * 2 + WSLACK);
    f16* wt_g3h  = (f16*)takeB((size_t)25 * 128 * 256 * 2 + WSLACK);

    // blocked padded cat buffers: [b][cblk][pixP][32], hi/lo planes
    const size_t cat1_n = (size_t)8 * 6 * 4624 * 32;   // 68x68, 192ch
    const size_t cat2_n = (size_t)8 * 12 * 1296 * 32;  // 36x36, 384ch
    const size_t cat3_n = (size_t)8 * 12 * 400 * 32;   // 20x20, 384ch
    const size_t ASLACK = 1 << 20;
    f16* cat1h = (f16*)takeB(cat1_n * 2 + ASLACK);
    f16* cat1l = (f16*)takeB(cat1_n * 2 + ASLACK);
    f16* cat2h = (f16*)takeB(cat2_n * 2 + ASLACK);
    f16* cat2l = (f16*)takeB(cat2_n * 2 + ASLACK);
    f16* cat3h = (f16*)takeB(cat3_n * 2 + ASLACK);
    f16* cat3l = (f16*)takeB(cat3_n * 2 + ASLACK);
    float* z1 = (float*)takeB((size_t)8 * 4096 * 64 * 4);
    float* z2 = (float*)takeB((size_t)8 * 1024 * 128 * 4);
    float* z3 = (float*)takeB((size_t)8 * 256 * 128 * 4);

    hipMemsetAsync(cat1h, 0, cat1_n * 2, stream);
    hipMemsetAsync(cat1l, 0, cat1_n * 2, stream);
    hipMemsetAsync(cat2h, 0, cat2_n * 2, stream);
    hipMemsetAsync(cat2l, 0, cat2_n * 2, stream);
    hipMemsetAsync(cat3h, 0, cat3_n * 2, stream);
    hipMemsetAsync(cat3l, 0, cat3_n * 2, stream);

    auto prep = [&](const float* w, f16* wt, int OC, int IC, int KK, int perm) {
        int total = OC * IC * KK;
        prep_w<<<(total + 255) / 256, 256, 0, stream>>>(w, wt, OC, IC, KK, perm);
    };
    prep(g1zr_w, wt_g1zr, 128, 128, 25, 1);
    prep(g1h_w,  wt_g1h,  64, 128, 25, 0);
    prep(c2_w,   wt_c2,   128, 64, 16, 0);
    prep(g2zr_w, wt_g2zr, 256, 256, 25, 1);
    prep(g2h_w,  wt_g2h,  128, 256, 25, 0);
    prep(c3_w,   wt_c3,   128, 128, 16, 0);
    prep(g3zr_w, wt_g3zr, 256, 256, 25, 1);
    prep(g3h_w,  wt_g3h,  128, 256, 25, 0);

    // Software-pipelined wavefront: iteration i runs stage1@t=i, stage2@t=i-1,
    // stage3@t=i-2.  12 steps -> 14 iterations (2 fill, 2 drain).
    for (int i = 0; i < 14; ++i) {
        const int t1 = (i < 12) ? i : -1;
        const int a1 = (i < 12) ? 1 : 0;
        const int a2 = (i >= 1 && i <= 12) ? 1 : 0;
        const int a3 = (i >= 2) ? 1 : 0;

        fused_L1<<<896, 256, 0, stream>>>(
            input, c1_w, c1_b, cat1h, cat1l,
            wt_c2, c2_b, cat2h, cat2l,
            wt_c3, c3_b, cat3h, cat3l,
            t1, a2, a3);
        fused_L2<<<1792, 256, 0, stream>>>(
            cat1h, cat1l, wt_g1zr, g1zr_b, z1,
            cat2h, cat2l, wt_g2zr, g2zr_b, z2,
            cat3h, cat3l, wt_g3zr, g3zr_b, z3,
            a1, a2, a3);
        fused_L3<<<896, 256, 0, stream>>>(
            cat1h, cat1l, wt_g1h, g1h_b, z1,
            cat2h, cat2l, wt_g2h, g2h_b, z2,
            cat3h, cat3l, wt_g3h, g3h_b, z3,
            a1, a2, a3);
    }

    cat_to_nchw<<<8192, 256, 0, stream>>>(cat1h, cat1l, out1, 64, 4096, 6, 68, 4624, 6);
    cat_to_nchw<<<4096, 256, 0, stream>>>(cat2h, cat2l, out2, 128, 1024, 5, 36, 1296, 12);
    cat_to_nchw<<<1024, 256, 0, stream>>>(cat3h, cat3l, out3, 128, 256, 4, 20, 400, 12);
}